// Round 6
// baseline (394.910 us; speedup 1.0000x reference)
//
#include <hip/hip_runtime.h>
#include <hip/hip_bf16.h>
#include <math.h>

// GNNStack: 3x GAT(heads=1, hid=64) + relu, then 64->64, 64->47, log_softmax.
//  - CSR build via two-level counting sort (no per-node global atomics).
//  - LIN/POST R6: wave = 16-col group, lane = node. W operand is read via
//    wave-uniform scalar loads (SMEM/K$, SGPR src to v_fmac) -> LDS pipe
//    carries only 1 conflict-free b32 per k (R5: 4x ds_read_b128 per k
//    saturated LDS pipe; post 62us @ VALUBusy 23%, lin0 occupancy 17.8%).
//  - H stored bf16 (halves gather bytes).
//  - AGG: group-parallel gather (4 edges/step via per-lane-index bpermute).

#define IN_DIM 128
#define HID 64
#define OUT_DIM 47
#define NEG_SLOPE 0.2f
#define EPS 1e-16f
#define BBITS 10
#define BN 1024
#define NBUCK_MAX 128

__device__ __forceinline__ float bflo(unsigned int d) {
    union { unsigned int i; float f; } c;
    c.i = d << 16;
    return c.f;
}
__device__ __forceinline__ float bfhi(unsigned int d) {
    union { unsigned int i; float f; } c;
    c.i = d & 0xffff0000u;
    return c.f;
}

// ---- CSR build: bucket histogram ----
__global__ __launch_bounds__(256) void bucket_count_kernel(const int* __restrict__ dst,
                                                           int* __restrict__ bcnt,
                                                           int e, int nbuck) {
    __shared__ int h[NBUCK_MAX];
    int tid = threadIdx.x;
    if (tid < nbuck) h[tid] = 0;
    __syncthreads();
    int chunk = (e + gridDim.x - 1) / gridDim.x;
    int beg = blockIdx.x * chunk, end = min(e, beg + chunk);
    for (int i = beg + tid; i < end; i += 256) atomicAdd(&h[dst[i] >> BBITS], 1);
    __syncthreads();
    if (tid < nbuck && h[tid]) atomicAdd(&bcnt[tid], h[tid]);
}

__global__ void bucket_scan_kernel(const int* __restrict__ bcnt, int* __restrict__ bbase,
                                   int* __restrict__ bfill, int nbuck) {
    if (threadIdx.x == 0 && blockIdx.x == 0) {
        int run = 0;
        for (int i = 0; i < nbuck; i++) { bbase[i] = run; bfill[i] = run; run += bcnt[i]; }
        bbase[nbuck] = run;
    }
}

__global__ __launch_bounds__(256) void bucket_scatter_kernel(const int* __restrict__ src,
                                                             const int* __restrict__ dst,
                                                             int* __restrict__ bfill,
                                                             int2* __restrict__ stg,
                                                             int e, int nbuck) {
    __shared__ int lcnt[NBUCK_MAX], lfill[NBUCK_MAX];
    int tid = threadIdx.x;
    if (tid < nbuck) lcnt[tid] = 0;
    __syncthreads();
    int chunk = (e + gridDim.x - 1) / gridDim.x;
    int beg = blockIdx.x * chunk, end = min(e, beg + chunk);
    for (int i = beg + tid; i < end; i += 256) atomicAdd(&lcnt[dst[i] >> BBITS], 1);
    __syncthreads();
    if (tid < nbuck) lfill[tid] = lcnt[tid] ? atomicAdd(&bfill[tid], lcnt[tid]) : 0;
    __syncthreads();
    for (int i = beg + tid; i < end; i += 256) {
        int d = dst[i];
        int p = atomicAdd(&lfill[d >> BBITS], 1);
        stg[p] = make_int2(src[i], d);
    }
}

__global__ __launch_bounds__(1024) void bucket_place_kernel(const int2* __restrict__ stg,
                                                            const int* __restrict__ bbase,
                                                            int* __restrict__ rowptr,
                                                            int* __restrict__ col,
                                                            int n, int e) {
    __shared__ int lcnt[BN];
    __shared__ int lscan[BN];
    __shared__ int lfill[BN];
    int tid = threadIdx.x, b = blockIdx.x;
    int node0 = b << BBITS;
    int ebeg = bbase[b], eend = bbase[b + 1];
    lcnt[tid] = 0;
    __syncthreads();
    for (int j = ebeg + tid; j < eend; j += 1024) atomicAdd(&lcnt[stg[j].y - node0], 1);
    __syncthreads();
    int v = lcnt[tid];
    lscan[tid] = v;
    __syncthreads();
    for (int off = 1; off < 1024; off <<= 1) {
        int t = (tid >= off) ? lscan[tid - off] : 0;
        __syncthreads();
        lscan[tid] += t;
        __syncthreads();
    }
    int gbase = ebeg + lscan[tid] - v;
    if (node0 + tid < n) rowptr[node0 + tid] = gbase;
    lfill[tid] = gbase;
    __syncthreads();
    for (int j = ebeg + tid; j < eend; j += 1024) {
        int2 ed = stg[j];
        int p = atomicAdd(&lfill[ed.y - node0], 1);
        col[p] = ed.x;
    }
    if (b == 0 && tid == 0) rowptr[n] = e;
}

// ---- lin: wave = 16-col group, lane = node; W via wave-uniform scalar loads ----
template <int DIN>
__global__ __launch_bounds__(256) void lin_swave_kernel(const float* __restrict__ X,
                                                        const float* __restrict__ W,
                                                        const float* __restrict__ B,
                                                        const float* __restrict__ attl,
                                                        const float* __restrict__ attr,
                                                        ushort* __restrict__ Hbf,
                                                        float* __restrict__ AL,
                                                        float* __restrict__ AR,
                                                        int n, int ntiles) {
    constexpr int P = DIN + 2;  // even (8B-aligned rows), stride%32=2 -> free 2-way alias
    __shared__ float Xl[64 * P];
    __shared__ float redl[4][64], redr[4][64];
    int tid = threadIdx.x;
    int wv = __builtin_amdgcn_readfirstlane(tid >> 6);
    int lane = tid & 63;
    int cg = wv << 4;
    // wave-uniform per-col constants (SGPR)
    float bs[16], as_l[16], as_r[16];
#pragma unroll
    for (int i = 0; i < 16; i++) {
        bs[i] = B[cg + i];
        as_l[i] = attl[cg + i];
        as_r[i] = attr[cg + i];
    }
    for (int tile = blockIdx.x; tile < ntiles; tile += gridDim.x) {
        __syncthreads();  // Xl/red reuse guard
        int node0 = tile << 6;
        for (int idx = tid; idx < 32 * DIN; idx += 256) {
            int flat = idx << 1;
            int rr = flat / DIN, kk = flat % DIN;
            int gsrc = min(node0 + rr, n - 1);
            *(float2*)&Xl[rr * P + kk] = *(const float2*)&X[(size_t)gsrc * DIN + kk];
        }
        __syncthreads();
        float acc[16];
#pragma unroll
        for (int i = 0; i < 16; i++) acc[i] = bs[i];
#pragma unroll 4
        for (int k = 0; k < DIN; k++) {
            float h = Xl[lane * P + k];
            const float* __restrict__ wr = &W[k * 64 + cg];  // wave-uniform -> s_load
#pragma unroll
            for (int i = 0; i < 16; i++) acc[i] = fmaf(h, wr[i], acc[i]);
        }
        float pl = 0.f, pr = 0.f;
#pragma unroll
        for (int i = 0; i < 16; i++) {
            pl = fmaf(acc[i], as_l[i], pl);
            pr = fmaf(acc[i], as_r[i], pr);
        }
        redl[wv][lane] = pl;
        redr[wv][lane] = pr;
        int node = node0 + lane;
        if (node < n) {
            unsigned int w[8];
#pragma unroll
            for (int i = 0; i < 8; i++) {
                __hip_bfloat16 lo = __float2bfloat16(acc[2 * i]);
                __hip_bfloat16 hi = __float2bfloat16(acc[2 * i + 1]);
                unsigned int lob = *(unsigned short*)&lo;
                unsigned int hib = *(unsigned short*)&hi;
                w[i] = lob | (hib << 16);
            }
            uint4* hp = (uint4*)&Hbf[(size_t)node * 64 + cg];
            hp[0] = make_uint4(w[0], w[1], w[2], w[3]);
            hp[1] = make_uint4(w[4], w[5], w[6], w[7]);
        }
        __syncthreads();
        if (wv == 0 && node < n) {
            AL[node] = redl[0][lane] + redl[1][lane] + redl[2][lane] + redl[3][lane];
            AR[node] = redr[0][lane] + redr[1][lane] + redr[2][lane] + redr[3][lane];
        }
    }
}

// ---- One wave per dst node: segment softmax + group-parallel gather ----
__global__ __launch_bounds__(256) void agg_kernel(const int* __restrict__ rowptr,
                                                  const int* __restrict__ col,
                                                  const float* __restrict__ AL,
                                                  const float* __restrict__ AR,
                                                  const ushort* __restrict__ Hbf,
                                                  float* __restrict__ OUT, int n) {
    int wv = threadIdx.x >> 6, lane = threadIdx.x & 63;
    int nidx = blockIdx.x * 4 + wv;
    if (nidx >= n) return;
    int beg = rowptr[nidx], end = rowptr[nidx + 1];
    int deg = end - beg;
    float ar_i = AR[nidx];
    int c0 = 0;
    float e0 = -INFINITY;
    if (lane < deg) {
        c0 = col[beg + lane];
        float t = AL[c0] + ar_i;
        e0 = t > 0.f ? t : NEG_SLOPE * t;
    }
    int c1 = 0;
    float e1 = -INFINITY;
    if (64 + lane < deg) {
        c1 = col[beg + 64 + lane];
        float t = AL[c1] + ar_i;
        e1 = t > 0.f ? t : NEG_SLOPE * t;
    }
    float mx = fmaxf(e0, e1);
    for (int j = beg + 128 + lane; j < end; j += 64) {
        float t = AL[col[j]] + ar_i;
        t = t > 0.f ? t : NEG_SLOPE * t;
        mx = fmaxf(mx, t);
    }
#pragma unroll
    for (int o = 32; o; o >>= 1) mx = fmaxf(mx, __shfl_xor(mx, o, 64));
    float x0 = (lane < deg) ? __expf(e0 - mx) : 0.f;
    float x1 = (64 + lane < deg) ? __expf(e1 - mx) : 0.f;
    float dl = x0 + x1;
    for (int j = beg + 128 + lane; j < end; j += 64) {
        float t = AL[col[j]] + ar_i;
        t = t > 0.f ? t : NEG_SLOPE * t;
        dl += __expf(t - mx);
    }
#pragma unroll
    for (int o = 32; o; o >>= 1) dl += __shfl_xor(dl, o, 64);
    int g = lane >> 4;
    unsigned int sub = (lane & 15) << 3;
    float a0 = 0.f, a1 = 0.f, a2 = 0.f, a3 = 0.f;
    int kend0 = deg < 64 ? deg : 64;
    for (int k = 0; k < kend0; k += 8) {
        int i0 = k + g, i1 = k + 4 + g;
        float w0 = __shfl(x0, i0, 64);
        int s0 = __shfl(c0, i0, 64);
        float w1 = __shfl(x0, i1, 64);
        int s1 = __shfl(c0, i1, 64);
        uint2 d0 = *(const uint2*)((const char*)Hbf + ((((unsigned)s0) << 7) + sub));
        uint2 d1 = *(const uint2*)((const char*)Hbf + ((((unsigned)s1) << 7) + sub));
        a0 = fmaf(w0, bflo(d0.x), a0);
        a1 = fmaf(w0, bfhi(d0.x), a1);
        a2 = fmaf(w0, bflo(d0.y), a2);
        a3 = fmaf(w0, bfhi(d0.y), a3);
        a0 = fmaf(w1, bflo(d1.x), a0);
        a1 = fmaf(w1, bfhi(d1.x), a1);
        a2 = fmaf(w1, bflo(d1.y), a2);
        a3 = fmaf(w1, bfhi(d1.y), a3);
    }
    if (deg > 64) {
        int kend1 = deg - 64 < 64 ? deg - 64 : 64;
        for (int k = 0; k < kend1; k += 8) {
            int i0 = k + g, i1 = k + 4 + g;
            float w0 = __shfl(x1, i0, 64);
            int s0 = __shfl(c1, i0, 64);
            float w1 = __shfl(x1, i1, 64);
            int s1 = __shfl(c1, i1, 64);
            uint2 d0 = *(const uint2*)((const char*)Hbf + ((((unsigned)s0) << 7) + sub));
            uint2 d1 = *(const uint2*)((const char*)Hbf + ((((unsigned)s1) << 7) + sub));
            a0 = fmaf(w0, bflo(d0.x), a0);
            a1 = fmaf(w0, bfhi(d0.x), a1);
            a2 = fmaf(w0, bflo(d0.y), a2);
            a3 = fmaf(w0, bfhi(d0.y), a3);
            a0 = fmaf(w1, bflo(d1.x), a0);
            a1 = fmaf(w1, bfhi(d1.x), a1);
            a2 = fmaf(w1, bflo(d1.y), a2);
            a3 = fmaf(w1, bfhi(d1.y), a3);
        }
        for (int j = beg + 128; j < end; j++) {
            int s = col[j];
            float t = AL[s] + ar_i;
            t = t > 0.f ? t : NEG_SLOPE * t;
            float ex = __expf(t - mx);
            uint2 d = *(const uint2*)((const char*)Hbf + ((((unsigned)s) << 7) + sub));
            a0 = fmaf(ex, bflo(d.x), a0);
            a1 = fmaf(ex, bfhi(d.x), a1);
            a2 = fmaf(ex, bflo(d.y), a2);
            a3 = fmaf(ex, bfhi(d.y), a3);
        }
    }
    a0 += __shfl_xor(a0, 16, 64);
    a0 += __shfl_xor(a0, 32, 64);
    a1 += __shfl_xor(a1, 16, 64);
    a1 += __shfl_xor(a1, 32, 64);
    a2 += __shfl_xor(a2, 16, 64);
    a2 += __shfl_xor(a2, 32, 64);
    a3 += __shfl_xor(a3, 16, 64);
    a3 += __shfl_xor(a3, 32, 64);
    if (g == 0) {
        float r = 1.0f / (dl + EPS);
        float o0 = a0 * r, o1 = a1 * r, o2 = a2 * r, o3 = a3 * r;
        o0 = o0 > 0.f ? o0 : 0.f;
        o1 = o1 > 0.f ? o1 : 0.f;
        o2 = o2 > 0.f ? o2 : 0.f;
        o3 = o3 > 0.f ? o3 : 0.f;
        *(float4*)((char*)OUT + (((size_t)nidx) << 8) + (sub << 1)) =
            make_float4(o0, o1, o2, o3);
    }
}

// ---- post: wave = 16-col group, lane = node; scalar W loads; 2 GEMMs + lsm ----
__global__ __launch_bounds__(256) void post_swave_kernel(const float* __restrict__ H3,
                                                         const float* __restrict__ Wp1,
                                                         const float* __restrict__ bp1,
                                                         const float* __restrict__ Wp2,
                                                         const float* __restrict__ bp2,
                                                         float* __restrict__ OUT,
                                                         int n, int ntiles) {
    constexpr int P = 66;
    __shared__ float Hl[64 * P];
    __shared__ float redm[4][64], reds[4][64];
    int tid = threadIdx.x;
    int wv = __builtin_amdgcn_readfirstlane(tid >> 6);
    int lane = tid & 63;
    int cg = wv << 4;
    float b1s[16], b2s[16];
#pragma unroll
    for (int i = 0; i < 16; i++) {
        b1s[i] = bp1[cg + i];
        b2s[i] = (cg + i < OUT_DIM) ? bp2[cg + i] : 0.f;
    }
    for (int tile = blockIdx.x; tile < ntiles; tile += gridDim.x) {
        __syncthreads();  // Hl/red reuse guard
        int node0 = tile << 6;
        for (int idx = tid; idx < 32 * 64; idx += 256) {
            int flat = idx << 1;
            int rr = flat >> 6, kk = flat & 63;
            int gsrc = min(node0 + rr, n - 1);
            *(float2*)&Hl[rr * P + kk] = *(const float2*)&H3[(size_t)gsrc * 64 + kk];
        }
        __syncthreads();
        // GEMM1: p = h @ W1 + b1 (scalar W reads)
        float acc[16];
#pragma unroll
        for (int i = 0; i < 16; i++) acc[i] = b1s[i];
#pragma unroll 4
        for (int k = 0; k < 64; k++) {
            float h = Hl[lane * P + k];
            const float* __restrict__ wr = &Wp1[k * 64 + cg];
#pragma unroll
            for (int i = 0; i < 16; i++) acc[i] = fmaf(h, wr[i], acc[i]);
        }
        __syncthreads();  // all GEMM1 reads of Hl done before p overwrite
#pragma unroll
        for (int i = 0; i < 8; i++)
            *(float2*)&Hl[lane * P + cg + 2 * i] = make_float2(acc[2 * i], acc[2 * i + 1]);
        __syncthreads();
        // GEMM2: q = p @ W2 + b2 (cols >= 47 unused; wave 3 idles)
        float m_part = -INFINITY, s_part = 0.f;
        float acc2[16];
        if (cg < OUT_DIM) {
#pragma unroll
            for (int i = 0; i < 16; i++) acc2[i] = b2s[i];
#pragma unroll 4
            for (int k = 0; k < 64; k++) {
                float p = Hl[lane * P + k];
                const float* __restrict__ wr = &Wp2[k * OUT_DIM];
#pragma unroll
                for (int i = 0; i < 16; i++) {
                    int c = cg + i;
                    float w = (c < OUT_DIM) ? wr[c < OUT_DIM ? c : OUT_DIM - 1] : 0.f;
                    acc2[i] = fmaf(p, w, acc2[i]);
                }
            }
#pragma unroll
            for (int i = 0; i < 16; i++)
                if (cg + i < OUT_DIM) m_part = fmaxf(m_part, acc2[i]);
        }
        redm[wv][lane] = m_part;
        __syncthreads();
        float m = fmaxf(fmaxf(redm[0][lane], redm[1][lane]),
                        fmaxf(redm[2][lane], redm[3][lane]));
        if (cg < OUT_DIM) {
#pragma unroll
            for (int i = 0; i < 16; i++)
                if (cg + i < OUT_DIM) s_part += __expf(acc2[i] - m);
        }
        reds[wv][lane] = s_part;
        __syncthreads();
        float s = reds[0][lane] + reds[1][lane] + reds[2][lane] + reds[3][lane];
        float lg = m + __logf(s);
        int node = node0 + lane;
        if (node < n && cg < OUT_DIM) {
            float* op = &OUT[(size_t)node * OUT_DIM + cg];
#pragma unroll
            for (int i = 0; i < 16; i++)
                if (cg + i < OUT_DIM) op[i] = acc2[i] - lg;
        }
    }
}

extern "C" void kernel_launch(void* const* d_in, const int* in_sizes, int n_in,
                              void* d_out, int out_size, void* d_ws, size_t ws_size,
                              hipStream_t stream) {
    const float* x = (const float*)d_in[0];
    const int* ei = (const int*)d_in[1];
    const float* W0 = (const float*)d_in[2];
    const float* b0 = (const float*)d_in[3];
    const float* al0 = (const float*)d_in[4];
    const float* ar0 = (const float*)d_in[5];
    const float* W1 = (const float*)d_in[6];
    const float* b1 = (const float*)d_in[7];
    const float* al1 = (const float*)d_in[8];
    const float* ar1 = (const float*)d_in[9];
    const float* W2 = (const float*)d_in[10];
    const float* b2 = (const float*)d_in[11];
    const float* al2 = (const float*)d_in[12];
    const float* ar2 = (const float*)d_in[13];
    const float* Wp1 = (const float*)d_in[14];
    const float* bp1 = (const float*)d_in[15];
    const float* Wp2 = (const float*)d_in[16];
    const float* bp2 = (const float*)d_in[17];
    float* out = (float*)d_out;

    const int N = in_sizes[0] / IN_DIM;
    const int E = in_sizes[1] / 2;
    const int NBUCK = (N + BN - 1) >> BBITS;
    const int NTILES = (N + 63) >> 6;

    char* ws = (char*)d_ws;
    float* Hf = (float*)ws;      ws += (size_t)N * 64 * sizeof(float);   // agg out / lin in
    ushort* Hbf = (ushort*)ws;   ws += (size_t)N * 64 * sizeof(ushort);  // lin out / agg gather
    float* ALb = (float*)ws;     ws += (size_t)N * sizeof(float);
    float* ARb = (float*)ws;     ws += (size_t)N * sizeof(float);
    int* rowptr = (int*)ws;      ws += (size_t)(N + 1) * sizeof(int);
    int* col = (int*)ws;         ws += (size_t)E * sizeof(int);
    int* bcnt = (int*)ws;        ws += (size_t)NBUCK * sizeof(int);
    int* bbase = (int*)ws;       ws += (size_t)(NBUCK + 1) * sizeof(int);
    int* bfill = (int*)ws;       ws += (size_t)NBUCK * sizeof(int);
    int2* stg = (int2*)Hf;  // staging aliases Hf (dead until agg0 writes it)

    const int* src = ei;
    const int* dst = ei + E;

    // ---- build CSR by dst: two-level counting sort ----
    hipMemsetAsync(bcnt, 0, (size_t)NBUCK * sizeof(int), stream);
    bucket_count_kernel<<<256, 256, 0, stream>>>(dst, bcnt, E, NBUCK);
    bucket_scan_kernel<<<1, 64, 0, stream>>>(bcnt, bbase, bfill, NBUCK);
    bucket_scatter_kernel<<<256, 256, 0, stream>>>(src, dst, bfill, stg, E, NBUCK);
    bucket_place_kernel<<<NBUCK, 1024, 0, stream>>>(stg, bbase, rowptr, col, N, E);

    int agg_grid = (N + 3) / 4;

    // ---- layer 0 ----
    lin_swave_kernel<IN_DIM><<<1024, 256, 0, stream>>>(x, W0, b0, al0, ar0, Hbf, ALb, ARb, N, NTILES);
    agg_kernel<<<agg_grid, 256, 0, stream>>>(rowptr, col, ALb, ARb, Hbf, Hf, N);
    // ---- layer 1 ----
    lin_swave_kernel<HID><<<1024, 256, 0, stream>>>(Hf, W1, b1, al1, ar1, Hbf, ALb, ARb, N, NTILES);
    agg_kernel<<<agg_grid, 256, 0, stream>>>(rowptr, col, ALb, ARb, Hbf, Hf, N);
    // ---- layer 2 ----
    lin_swave_kernel<HID><<<1024, 256, 0, stream>>>(Hf, W2, b2, al2, ar2, Hbf, ALb, ARb, N, NTILES);
    agg_kernel<<<agg_grid, 256, 0, stream>>>(rowptr, col, ALb, ARb, Hbf, Hf, N);
    // ---- post ----
    post_swave_kernel<<<1024, 256, 0, stream>>>(Hf, Wp1, bp1, Wp2, bp2, out, N, NTILES);
}

// Round 7
// 327.510 us; speedup vs baseline: 1.2058x; 1.2058x over previous
//
#include <hip/hip_runtime.h>
#include <hip/hip_bf16.h>
#include <math.h>

// GNNStack: 3x GAT(heads=1, hid=64) + relu, then 64->64, 64->47, log_softmax.
//  - CSR build via two-level counting sort (no per-node global atomics).
//  - LIN/POST R7: MFMA (16x16x32 bf16). A = 64-node tile row-major bf16 LDS
//    (+8 pad), B = W transposed bf16 LDS (Wt[c][k], staged once per block).
//    Wave = 16-col slice, 4 row-blocks, acc 4x f32x4. C/D: col=lane&15,
//    row=(lane>>4)*4+reg. alpha dots -> separate tiny kernel.
//  - AGG: group-parallel gather (R5, unchanged).

#define IN_DIM 128
#define HID 64
#define OUT_DIM 47
#define NEG_SLOPE 0.2f
#define EPS 1e-16f
#define BBITS 10
#define BN 1024
#define NBUCK_MAX 128

typedef short bf16x8 __attribute__((ext_vector_type(8)));
typedef float f32x4 __attribute__((ext_vector_type(4)));

__device__ __forceinline__ float bflo(unsigned int d) {
    union { unsigned int i; float f; } c;
    c.i = d << 16;
    return c.f;
}
__device__ __forceinline__ float bfhi(unsigned int d) {
    union { unsigned int i; float f; } c;
    c.i = d & 0xffff0000u;
    return c.f;
}
__device__ __forceinline__ ushort f2bf(float f) {
    __hip_bfloat16 b = __float2bfloat16(f);
    return *(ushort*)&b;
}

// ---- CSR build: bucket histogram ----
__global__ __launch_bounds__(256) void bucket_count_kernel(const int* __restrict__ dst,
                                                           int* __restrict__ bcnt,
                                                           int e, int nbuck) {
    __shared__ int h[NBUCK_MAX];
    int tid = threadIdx.x;
    if (tid < nbuck) h[tid] = 0;
    __syncthreads();
    int chunk = (e + gridDim.x - 1) / gridDim.x;
    int beg = blockIdx.x * chunk, end = min(e, beg + chunk);
    for (int i = beg + tid; i < end; i += 256) atomicAdd(&h[dst[i] >> BBITS], 1);
    __syncthreads();
    if (tid < nbuck && h[tid]) atomicAdd(&bcnt[tid], h[tid]);
}

__global__ void bucket_scan_kernel(const int* __restrict__ bcnt, int* __restrict__ bbase,
                                   int* __restrict__ bfill, int nbuck) {
    if (threadIdx.x == 0 && blockIdx.x == 0) {
        int run = 0;
        for (int i = 0; i < nbuck; i++) { bbase[i] = run; bfill[i] = run; run += bcnt[i]; }
        bbase[nbuck] = run;
    }
}

__global__ __launch_bounds__(256) void bucket_scatter_kernel(const int* __restrict__ src,
                                                             const int* __restrict__ dst,
                                                             int* __restrict__ bfill,
                                                             int2* __restrict__ stg,
                                                             int e, int nbuck) {
    __shared__ int lcnt[NBUCK_MAX], lfill[NBUCK_MAX];
    int tid = threadIdx.x;
    if (tid < nbuck) lcnt[tid] = 0;
    __syncthreads();
    int chunk = (e + gridDim.x - 1) / gridDim.x;
    int beg = blockIdx.x * chunk, end = min(e, beg + chunk);
    for (int i = beg + tid; i < end; i += 256) atomicAdd(&lcnt[dst[i] >> BBITS], 1);
    __syncthreads();
    if (tid < nbuck) lfill[tid] = lcnt[tid] ? atomicAdd(&bfill[tid], lcnt[tid]) : 0;
    __syncthreads();
    for (int i = beg + tid; i < end; i += 256) {
        int d = dst[i];
        int p = atomicAdd(&lfill[d >> BBITS], 1);
        stg[p] = make_int2(src[i], d);
    }
}

__global__ __launch_bounds__(1024) void bucket_place_kernel(const int2* __restrict__ stg,
                                                            const int* __restrict__ bbase,
                                                            int* __restrict__ rowptr,
                                                            int* __restrict__ col,
                                                            int n, int e) {
    __shared__ int lcnt[BN];
    __shared__ int lscan[BN];
    __shared__ int lfill[BN];
    int tid = threadIdx.x, b = blockIdx.x;
    int node0 = b << BBITS;
    int ebeg = bbase[b], eend = bbase[b + 1];
    lcnt[tid] = 0;
    __syncthreads();
    for (int j = ebeg + tid; j < eend; j += 1024) atomicAdd(&lcnt[stg[j].y - node0], 1);
    __syncthreads();
    int v = lcnt[tid];
    lscan[tid] = v;
    __syncthreads();
    for (int off = 1; off < 1024; off <<= 1) {
        int t = (tid >= off) ? lscan[tid - off] : 0;
        __syncthreads();
        lscan[tid] += t;
        __syncthreads();
    }
    int gbase = ebeg + lscan[tid] - v;
    if (node0 + tid < n) rowptr[node0 + tid] = gbase;
    lfill[tid] = gbase;
    __syncthreads();
    for (int j = ebeg + tid; j < eend; j += 1024) {
        int2 ed = stg[j];
        int p = atomicAdd(&lfill[ed.y - node0], 1);
        col[p] = ed.x;
    }
    if (b == 0 && tid == 0) rowptr[n] = e;
}

// ---- MFMA lin: H = bf16(X) @ bf16(W) + b, tile = 64 nodes x 64 cols ----
template <int DIN>
__global__ __launch_bounds__(256) void lin_mfma_kernel(const float* __restrict__ X,
                                                       const float* __restrict__ W,
                                                       const float* __restrict__ B,
                                                       ushort* __restrict__ Hbf,
                                                       int n, int ntiles) {
    constexpr int PS = DIN + 8;  // bf16 stride: 16B-aligned rows, 2-way banks
    __shared__ ushort Xl[64 * PS];
    __shared__ ushort Wt[64 * PS];  // Wt[c][k] = W[k][c]
    int tid = threadIdx.x;
    int lane = tid & 63;
    int cb = (tid >> 6) << 4;  // wave's col base
    int colin = lane & 15, ksel = lane >> 4;
    // stage Wt once per block (coalesced float4 reads, b16 transposed writes)
    for (int i = tid; i < DIN * 16; i += 256) {
        int k = i >> 4, cq = i & 15;
        float4 w = *(const float4*)&W[k * 64 + cq * 4];
        Wt[(cq * 4 + 0) * PS + k] = f2bf(w.x);
        Wt[(cq * 4 + 1) * PS + k] = f2bf(w.y);
        Wt[(cq * 4 + 2) * PS + k] = f2bf(w.z);
        Wt[(cq * 4 + 3) * PS + k] = f2bf(w.w);
    }
    float bc = B[cb + colin];  // bias for this lane's output col
    for (int tile = blockIdx.x; tile < ntiles; tile += gridDim.x) {
        __syncthreads();  // prev compute done before restage (also covers Wt)
        int node0 = tile << 6;
        for (int i = tid; i < DIN * 16; i += 256) {
            int flat = i << 2;
            int rr = flat / DIN, kk = flat % DIN;
            int gsrc = min(node0 + rr, n - 1);
            float4 v = *(const float4*)&X[(size_t)gsrc * DIN + kk];
            ushort4 u;
            u.x = f2bf(v.x);
            u.y = f2bf(v.y);
            u.z = f2bf(v.z);
            u.w = f2bf(v.w);
            *(ushort4*)&Xl[rr * PS + kk] = u;
        }
        __syncthreads();
        f32x4 acc[4];
#pragma unroll
        for (int rb = 0; rb < 4; rb++) acc[rb] = (f32x4){bc, bc, bc, bc};
#pragma unroll
        for (int ks = 0; ks < DIN; ks += 32) {
            bf16x8 bfr = *(const bf16x8*)&Wt[(cb + colin) * PS + ks + ksel * 8];
#pragma unroll
            for (int rb = 0; rb < 4; rb++) {
                bf16x8 afr = *(const bf16x8*)&Xl[(rb * 16 + colin) * PS + ks + ksel * 8];
                acc[rb] = __builtin_amdgcn_mfma_f32_16x16x32_bf16(afr, bfr, acc[rb], 0, 0, 0);
            }
        }
        // D layout: col = cb+colin, row = rb*16 + ksel*4 + r
#pragma unroll
        for (int rb = 0; rb < 4; rb++) {
#pragma unroll
            for (int r = 0; r < 4; r++) {
                int node = node0 + rb * 16 + ksel * 4 + r;
                if (node < n) Hbf[(size_t)node * 64 + cb + colin] = f2bf(acc[rb][r]);
            }
        }
    }
}

// ---- alpha: AL[n] = h[n].al, AR[n] = h[n].ar from bf16 H (one wave/node) ----
__global__ __launch_bounds__(256) void alpha_kernel(const ushort* __restrict__ Hbf,
                                                    const float* __restrict__ attl,
                                                    const float* __restrict__ attr,
                                                    float* __restrict__ AL,
                                                    float* __restrict__ AR, int n) {
    int wv = threadIdx.x >> 6, lane = threadIdx.x & 63;
    int nd = blockIdx.x * 4 + wv;
    if (nd >= n) return;
    float h = bflo(Hbf[(size_t)nd * 64 + lane]);
    float pl = h * attl[lane], pr = h * attr[lane];
#pragma unroll
    for (int o = 32; o; o >>= 1) {
        pl += __shfl_xor(pl, o, 64);
        pr += __shfl_xor(pr, o, 64);
    }
    if (lane == 0) {
        AL[nd] = pl;
        AR[nd] = pr;
    }
}

// ---- One wave per dst node: segment softmax + group-parallel gather ----
__global__ __launch_bounds__(256) void agg_kernel(const int* __restrict__ rowptr,
                                                  const int* __restrict__ col,
                                                  const float* __restrict__ AL,
                                                  const float* __restrict__ AR,
                                                  const ushort* __restrict__ Hbf,
                                                  float* __restrict__ OUT, int n) {
    int wv = threadIdx.x >> 6, lane = threadIdx.x & 63;
    int nidx = blockIdx.x * 4 + wv;
    if (nidx >= n) return;
    int beg = rowptr[nidx], end = rowptr[nidx + 1];
    int deg = end - beg;
    float ar_i = AR[nidx];
    int c0 = 0;
    float e0 = -INFINITY;
    if (lane < deg) {
        c0 = col[beg + lane];
        float t = AL[c0] + ar_i;
        e0 = t > 0.f ? t : NEG_SLOPE * t;
    }
    int c1 = 0;
    float e1 = -INFINITY;
    if (64 + lane < deg) {
        c1 = col[beg + 64 + lane];
        float t = AL[c1] + ar_i;
        e1 = t > 0.f ? t : NEG_SLOPE * t;
    }
    float mx = fmaxf(e0, e1);
    for (int j = beg + 128 + lane; j < end; j += 64) {
        float t = AL[col[j]] + ar_i;
        t = t > 0.f ? t : NEG_SLOPE * t;
        mx = fmaxf(mx, t);
    }
#pragma unroll
    for (int o = 32; o; o >>= 1) mx = fmaxf(mx, __shfl_xor(mx, o, 64));
    float x0 = (lane < deg) ? __expf(e0 - mx) : 0.f;
    float x1 = (64 + lane < deg) ? __expf(e1 - mx) : 0.f;
    float dl = x0 + x1;
    for (int j = beg + 128 + lane; j < end; j += 64) {
        float t = AL[col[j]] + ar_i;
        t = t > 0.f ? t : NEG_SLOPE * t;
        dl += __expf(t - mx);
    }
#pragma unroll
    for (int o = 32; o; o >>= 1) dl += __shfl_xor(dl, o, 64);
    int g = lane >> 4;
    unsigned int sub = (lane & 15) << 3;
    float a0 = 0.f, a1 = 0.f, a2 = 0.f, a3 = 0.f;
    int kend0 = deg < 64 ? deg : 64;
    for (int k = 0; k < kend0; k += 8) {
        int i0 = k + g, i1 = k + 4 + g;
        float w0 = __shfl(x0, i0, 64);
        int s0 = __shfl(c0, i0, 64);
        float w1 = __shfl(x0, i1, 64);
        int s1 = __shfl(c0, i1, 64);
        uint2 d0 = *(const uint2*)((const char*)Hbf + ((((unsigned)s0) << 7) + sub));
        uint2 d1 = *(const uint2*)((const char*)Hbf + ((((unsigned)s1) << 7) + sub));
        a0 = fmaf(w0, bflo(d0.x), a0);
        a1 = fmaf(w0, bfhi(d0.x), a1);
        a2 = fmaf(w0, bflo(d0.y), a2);
        a3 = fmaf(w0, bfhi(d0.y), a3);
        a0 = fmaf(w1, bflo(d1.x), a0);
        a1 = fmaf(w1, bfhi(d1.x), a1);
        a2 = fmaf(w1, bflo(d1.y), a2);
        a3 = fmaf(w1, bfhi(d1.y), a3);
    }
    if (deg > 64) {
        int kend1 = deg - 64 < 64 ? deg - 64 : 64;
        for (int k = 0; k < kend1; k += 8) {
            int i0 = k + g, i1 = k + 4 + g;
            float w0 = __shfl(x1, i0, 64);
            int s0 = __shfl(c1, i0, 64);
            float w1 = __shfl(x1, i1, 64);
            int s1 = __shfl(c1, i1, 64);
            uint2 d0 = *(const uint2*)((const char*)Hbf + ((((unsigned)s0) << 7) + sub));
            uint2 d1 = *(const uint2*)((const char*)Hbf + ((((unsigned)s1) << 7) + sub));
            a0 = fmaf(w0, bflo(d0.x), a0);
            a1 = fmaf(w0, bfhi(d0.x), a1);
            a2 = fmaf(w0, bflo(d0.y), a2);
            a3 = fmaf(w0, bfhi(d0.y), a3);
            a0 = fmaf(w1, bflo(d1.x), a0);
            a1 = fmaf(w1, bfhi(d1.x), a1);
            a2 = fmaf(w1, bflo(d1.y), a2);
            a3 = fmaf(w1, bfhi(d1.y), a3);
        }
        for (int j = beg + 128; j < end; j++) {
            int s = col[j];
            float t = AL[s] + ar_i;
            t = t > 0.f ? t : NEG_SLOPE * t;
            float ex = __expf(t - mx);
            uint2 d = *(const uint2*)((const char*)Hbf + ((((unsigned)s) << 7) + sub));
            a0 = fmaf(ex, bflo(d.x), a0);
            a1 = fmaf(ex, bfhi(d.x), a1);
            a2 = fmaf(ex, bflo(d.y), a2);
            a3 = fmaf(ex, bfhi(d.y), a3);
        }
    }
    a0 += __shfl_xor(a0, 16, 64);
    a0 += __shfl_xor(a0, 32, 64);
    a1 += __shfl_xor(a1, 16, 64);
    a1 += __shfl_xor(a1, 32, 64);
    a2 += __shfl_xor(a2, 16, 64);
    a2 += __shfl_xor(a2, 32, 64);
    a3 += __shfl_xor(a3, 16, 64);
    a3 += __shfl_xor(a3, 32, 64);
    if (g == 0) {
        float r = 1.0f / (dl + EPS);
        float o0 = a0 * r, o1 = a1 * r, o2 = a2 * r, o3 = a3 * r;
        o0 = o0 > 0.f ? o0 : 0.f;
        o1 = o1 > 0.f ? o1 : 0.f;
        o2 = o2 > 0.f ? o2 : 0.f;
        o3 = o3 > 0.f ? o3 : 0.f;
        *(float4*)((char*)OUT + (((size_t)nidx) << 8) + (sub << 1)) =
            make_float4(o0, o1, o2, o3);
    }
}

// ---- MFMA post: q = (h3@W1+b1)@W2+b2 ; log_softmax ----
__global__ __launch_bounds__(256) void post_mfma_kernel(const float* __restrict__ H3,
                                                        const float* __restrict__ Wp1,
                                                        const float* __restrict__ bp1,
                                                        const float* __restrict__ Wp2,
                                                        const float* __restrict__ bp2,
                                                        float* __restrict__ OUT,
                                                        int n, int ntiles) {
    constexpr int PS = 72;  // 64 + 8 pad (bf16)
    __shared__ ushort Hl[64 * PS];
    __shared__ ushort Pl[64 * PS];
    __shared__ ushort Wt1[64 * PS];
    __shared__ ushort Wt2[64 * PS];
    __shared__ float Ql[64 * PS];
    int tid = threadIdx.x;
    int lane = tid & 63;
    int cb = (tid >> 6) << 4;
    int colin = lane & 15, ksel = lane >> 4;
    // stage transposed weights once (W2 cols >= 47 zeroed)
    for (int i = tid; i < 64 * 16; i += 256) {
        int k = i >> 4, cq = i & 15;
        float4 w1 = *(const float4*)&Wp1[k * 64 + cq * 4];
        Wt1[(cq * 4 + 0) * PS + k] = f2bf(w1.x);
        Wt1[(cq * 4 + 1) * PS + k] = f2bf(w1.y);
        Wt1[(cq * 4 + 2) * PS + k] = f2bf(w1.z);
        Wt1[(cq * 4 + 3) * PS + k] = f2bf(w1.w);
#pragma unroll
        for (int j = 0; j < 4; j++) {
            int c = cq * 4 + j;
            float w2 = (c < OUT_DIM) ? Wp2[k * OUT_DIM + c] : 0.f;
            Wt2[c * PS + k] = f2bf(w2);
        }
    }
    int myc = cb + colin;
    float bc1 = bp1[myc];
    float bc2 = (myc < OUT_DIM) ? bp2[myc] : 0.f;
    for (int tile = blockIdx.x; tile < ntiles; tile += gridDim.x) {
        __syncthreads();  // prev iter fully done (also covers Wt stage)
        int node0 = tile << 6;
        for (int i = tid; i < 64 * 16; i += 256) {
            int flat = i << 2;
            int rr = flat >> 6, kk = flat & 63;
            int gsrc = min(node0 + rr, n - 1);
            float4 v = *(const float4*)&H3[(size_t)gsrc * 64 + kk];
            ushort4 u;
            u.x = f2bf(v.x);
            u.y = f2bf(v.y);
            u.z = f2bf(v.z);
            u.w = f2bf(v.w);
            *(ushort4*)&Hl[rr * PS + kk] = u;
        }
        __syncthreads();
        // GEMM1: p = h @ W1 + b1
        f32x4 acc1[4];
#pragma unroll
        for (int rb = 0; rb < 4; rb++) acc1[rb] = (f32x4){bc1, bc1, bc1, bc1};
#pragma unroll
        for (int ks = 0; ks < 64; ks += 32) {
            bf16x8 bfr = *(const bf16x8*)&Wt1[myc * PS + ks + ksel * 8];
#pragma unroll
            for (int rb = 0; rb < 4; rb++) {
                bf16x8 afr = *(const bf16x8*)&Hl[(rb * 16 + colin) * PS + ks + ksel * 8];
                acc1[rb] = __builtin_amdgcn_mfma_f32_16x16x32_bf16(afr, bfr, acc1[rb], 0, 0, 0);
            }
        }
#pragma unroll
        for (int rb = 0; rb < 4; rb++) {
#pragma unroll
            for (int r = 0; r < 4; r++) {
                int row = rb * 16 + ksel * 4 + r;
                Pl[row * PS + myc] = f2bf(acc1[rb][r]);
            }
        }
        __syncthreads();
        // GEMM2: q = p @ W2 + b2
        f32x4 acc2[4];
#pragma unroll
        for (int rb = 0; rb < 4; rb++) acc2[rb] = (f32x4){bc2, bc2, bc2, bc2};
#pragma unroll
        for (int ks = 0; ks < 64; ks += 32) {
            bf16x8 bfr = *(const bf16x8*)&Wt2[myc * PS + ks + ksel * 8];
#pragma unroll
            for (int rb = 0; rb < 4; rb++) {
                bf16x8 afr = *(const bf16x8*)&Pl[(rb * 16 + colin) * PS + ks + ksel * 8];
                acc2[rb] = __builtin_amdgcn_mfma_f32_16x16x32_bf16(afr, bfr, acc2[rb], 0, 0, 0);
            }
        }
#pragma unroll
        for (int rb = 0; rb < 4; rb++) {
#pragma unroll
            for (int r = 0; r < 4; r++) {
                int row = rb * 16 + ksel * 4 + r;
                Ql[row * PS + myc] = acc2[rb][r];
            }
        }
        __syncthreads();
        // log_softmax: 4 threads per node, 12 cols each
        int nd = tid >> 2, part = tid & 3;
        int cbeg = part * 12;
        float m = -INFINITY;
#pragma unroll
        for (int i = 0; i < 12; i++) {
            int c = cbeg + i;
            if (c < OUT_DIM) m = fmaxf(m, Ql[nd * PS + c]);
        }
        m = fmaxf(m, __shfl_xor(m, 1, 64));
        m = fmaxf(m, __shfl_xor(m, 2, 64));
        float s = 0.f;
#pragma unroll
        for (int i = 0; i < 12; i++) {
            int c = cbeg + i;
            if (c < OUT_DIM) s += __expf(Ql[nd * PS + c] - m);
        }
        s += __shfl_xor(s, 1, 64);
        s += __shfl_xor(s, 2, 64);
        float lg = m + __logf(s);
        int node = node0 + nd;
        if (node < n) {
#pragma unroll
            for (int i = 0; i < 12; i++) {
                int c = cbeg + i;
                if (c < OUT_DIM) OUT[(size_t)node * OUT_DIM + c] = Ql[nd * PS + c] - lg;
            }
        }
    }
}

extern "C" void kernel_launch(void* const* d_in, const int* in_sizes, int n_in,
                              void* d_out, int out_size, void* d_ws, size_t ws_size,
                              hipStream_t stream) {
    const float* x = (const float*)d_in[0];
    const int* ei = (const int*)d_in[1];
    const float* W0 = (const float*)d_in[2];
    const float* b0 = (const float*)d_in[3];
    const float* al0 = (const float*)d_in[4];
    const float* ar0 = (const float*)d_in[5];
    const float* W1 = (const float*)d_in[6];
    const float* b1 = (const float*)d_in[7];
    const float* al1 = (const float*)d_in[8];
    const float* ar1 = (const float*)d_in[9];
    const float* W2 = (const float*)d_in[10];
    const float* b2 = (const float*)d_in[11];
    const float* al2 = (const float*)d_in[12];
    const float* ar2 = (const float*)d_in[13];
    const float* Wp1 = (const float*)d_in[14];
    const float* bp1 = (const float*)d_in[15];
    const float* Wp2 = (const float*)d_in[16];
    const float* bp2 = (const float*)d_in[17];
    float* out = (float*)d_out;

    const int N = in_sizes[0] / IN_DIM;
    const int E = in_sizes[1] / 2;
    const int NBUCK = (N + BN - 1) >> BBITS;
    const int NTILES = (N + 63) >> 6;

    char* ws = (char*)d_ws;
    float* Hf = (float*)ws;      ws += (size_t)N * 64 * sizeof(float);   // agg out / lin in
    ushort* Hbf = (ushort*)ws;   ws += (size_t)N * 64 * sizeof(ushort);  // lin out / agg gather
    float* ALb = (float*)ws;     ws += (size_t)N * sizeof(float);
    float* ARb = (float*)ws;     ws += (size_t)N * sizeof(float);
    int* rowptr = (int*)ws;      ws += (size_t)(N + 1) * sizeof(int);
    int* col = (int*)ws;         ws += (size_t)E * sizeof(int);
    int* bcnt = (int*)ws;        ws += (size_t)NBUCK * sizeof(int);
    int* bbase = (int*)ws;       ws += (size_t)(NBUCK + 1) * sizeof(int);
    int* bfill = (int*)ws;       ws += (size_t)NBUCK * sizeof(int);
    int2* stg = (int2*)Hf;  // staging aliases Hf (dead until agg0 writes it)

    const int* src = ei;
    const int* dst = ei + E;

    // ---- build CSR by dst: two-level counting sort ----
    hipMemsetAsync(bcnt, 0, (size_t)NBUCK * sizeof(int), stream);
    bucket_count_kernel<<<256, 256, 0, stream>>>(dst, bcnt, E, NBUCK);
    bucket_scan_kernel<<<1, 64, 0, stream>>>(bcnt, bbase, bfill, NBUCK);
    bucket_scatter_kernel<<<256, 256, 0, stream>>>(src, dst, bfill, stg, E, NBUCK);
    bucket_place_kernel<<<NBUCK, 1024, 0, stream>>>(stg, bbase, rowptr, col, N, E);

    int agg_grid = (N + 3) / 4;
    int alpha_grid = (N + 3) / 4;

    // ---- layer 0 ----
    lin_mfma_kernel<IN_DIM><<<512, 256, 0, stream>>>(x, W0, b0, Hbf, N, NTILES);
    alpha_kernel<<<alpha_grid, 256, 0, stream>>>(Hbf, al0, ar0, ALb, ARb, N);
    agg_kernel<<<agg_grid, 256, 0, stream>>>(rowptr, col, ALb, ARb, Hbf, Hf, N);
    // ---- layer 1 ----
    lin_mfma_kernel<HID><<<512, 256, 0, stream>>>(Hf, W1, b1, Hbf, N, NTILES);
    alpha_kernel<<<alpha_grid, 256, 0, stream>>>(Hbf, al1, ar1, ALb, ARb, N);
    agg_kernel<<<agg_grid, 256, 0, stream>>>(rowptr, col, ALb, ARb, Hbf, Hf, N);
    // ---- layer 2 ----
    lin_mfma_kernel<HID><<<512, 256, 0, stream>>>(Hf, W2, b2, Hbf, N, NTILES);
    alpha_kernel<<<alpha_grid, 256, 0, stream>>>(Hbf, al2, ar2, ALb, ARb, N);
    agg_kernel<<<agg_grid, 256, 0, stream>>>(rowptr, col, ALb, ARb, Hbf, Hf, N);
    // ---- post ----
    post_mfma_kernel<<<512, 256, 0, stream>>>(Hf, Wp1, bp1, Wp2, bp2, out, N, NTILES);
}

// Round 8
// 307.216 us; speedup vs baseline: 1.2854x; 1.0661x over previous
//
#include <hip/hip_runtime.h>
#include <hip/hip_bf16.h>
#include <math.h>

// GNNStack: 3x GAT(heads=1, hid=64) + relu, then 64->64, 64->47, log_softmax.
//  - CSR build via two-level counting sort (no per-node global atomics).
//  - LIN/POST: MFMA 16x16x32 bf16 (R7).
//  - AGG R8: no segment-max pass (softmax shift-invariance; logits bounded
//    |e|<~3 so raw fp32 exp is safe); denom folded into the cross-group
//    reduction; deg<=32 fast path fully unrolled with all 8 gather loads
//    issued before consumption (R7 was latency-bound: 2 loads in flight,
//    VALUBusy 52%, HBM 28%).

#define IN_DIM 128
#define HID 64
#define OUT_DIM 47
#define NEG_SLOPE 0.2f
#define EPS 1e-16f
#define BBITS 10
#define BN 1024
#define NBUCK_MAX 128

typedef short bf16x8 __attribute__((ext_vector_type(8)));
typedef float f32x4 __attribute__((ext_vector_type(4)));

__device__ __forceinline__ float bflo(unsigned int d) {
    union { unsigned int i; float f; } c;
    c.i = d << 16;
    return c.f;
}
__device__ __forceinline__ float bfhi(unsigned int d) {
    union { unsigned int i; float f; } c;
    c.i = d & 0xffff0000u;
    return c.f;
}
__device__ __forceinline__ ushort f2bf(float f) {
    __hip_bfloat16 b = __float2bfloat16(f);
    return *(ushort*)&b;
}

// ---- CSR build: bucket histogram ----
__global__ __launch_bounds__(256) void bucket_count_kernel(const int* __restrict__ dst,
                                                           int* __restrict__ bcnt,
                                                           int e, int nbuck) {
    __shared__ int h[NBUCK_MAX];
    int tid = threadIdx.x;
    if (tid < nbuck) h[tid] = 0;
    __syncthreads();
    int chunk = (e + gridDim.x - 1) / gridDim.x;
    int beg = blockIdx.x * chunk, end = min(e, beg + chunk);
    for (int i = beg + tid; i < end; i += 256) atomicAdd(&h[dst[i] >> BBITS], 1);
    __syncthreads();
    if (tid < nbuck && h[tid]) atomicAdd(&bcnt[tid], h[tid]);
}

__global__ void bucket_scan_kernel(const int* __restrict__ bcnt, int* __restrict__ bbase,
                                   int* __restrict__ bfill, int nbuck) {
    if (threadIdx.x == 0 && blockIdx.x == 0) {
        int run = 0;
        for (int i = 0; i < nbuck; i++) { bbase[i] = run; bfill[i] = run; run += bcnt[i]; }
        bbase[nbuck] = run;
    }
}

__global__ __launch_bounds__(256) void bucket_scatter_kernel(const int* __restrict__ src,
                                                             const int* __restrict__ dst,
                                                             int* __restrict__ bfill,
                                                             int2* __restrict__ stg,
                                                             int e, int nbuck) {
    __shared__ int lcnt[NBUCK_MAX], lfill[NBUCK_MAX];
    int tid = threadIdx.x;
    if (tid < nbuck) lcnt[tid] = 0;
    __syncthreads();
    int chunk = (e + gridDim.x - 1) / gridDim.x;
    int beg = blockIdx.x * chunk, end = min(e, beg + chunk);
    for (int i = beg + tid; i < end; i += 256) atomicAdd(&lcnt[dst[i] >> BBITS], 1);
    __syncthreads();
    if (tid < nbuck) lfill[tid] = lcnt[tid] ? atomicAdd(&bfill[tid], lcnt[tid]) : 0;
    __syncthreads();
    for (int i = beg + tid; i < end; i += 256) {
        int d = dst[i];
        int p = atomicAdd(&lfill[d >> BBITS], 1);
        stg[p] = make_int2(src[i], d);
    }
}

__global__ __launch_bounds__(1024) void bucket_place_kernel(const int2* __restrict__ stg,
                                                            const int* __restrict__ bbase,
                                                            int* __restrict__ rowptr,
                                                            int* __restrict__ col,
                                                            int n, int e) {
    __shared__ int lcnt[BN];
    __shared__ int lscan[BN];
    __shared__ int lfill[BN];
    int tid = threadIdx.x, b = blockIdx.x;
    int node0 = b << BBITS;
    int ebeg = bbase[b], eend = bbase[b + 1];
    lcnt[tid] = 0;
    __syncthreads();
    for (int j = ebeg + tid; j < eend; j += 1024) atomicAdd(&lcnt[stg[j].y - node0], 1);
    __syncthreads();
    int v = lcnt[tid];
    lscan[tid] = v;
    __syncthreads();
    for (int off = 1; off < 1024; off <<= 1) {
        int t = (tid >= off) ? lscan[tid - off] : 0;
        __syncthreads();
        lscan[tid] += t;
        __syncthreads();
    }
    int gbase = ebeg + lscan[tid] - v;
    if (node0 + tid < n) rowptr[node0 + tid] = gbase;
    lfill[tid] = gbase;
    __syncthreads();
    for (int j = ebeg + tid; j < eend; j += 1024) {
        int2 ed = stg[j];
        int p = atomicAdd(&lfill[ed.y - node0], 1);
        col[p] = ed.x;
    }
    if (b == 0 && tid == 0) rowptr[n] = e;
}

// ---- MFMA lin: H = bf16(X) @ bf16(W) + b, tile = 64 nodes x 64 cols ----
template <int DIN>
__global__ __launch_bounds__(256) void lin_mfma_kernel(const float* __restrict__ X,
                                                       const float* __restrict__ W,
                                                       const float* __restrict__ B,
                                                       ushort* __restrict__ Hbf,
                                                       int n, int ntiles) {
    constexpr int PS = DIN + 8;
    __shared__ ushort Xl[64 * PS];
    __shared__ ushort Wt[64 * PS];  // Wt[c][k] = W[k][c]
    int tid = threadIdx.x;
    int lane = tid & 63;
    int cb = (tid >> 6) << 4;
    int colin = lane & 15, ksel = lane >> 4;
    for (int i = tid; i < DIN * 16; i += 256) {
        int k = i >> 4, cq = i & 15;
        float4 w = *(const float4*)&W[k * 64 + cq * 4];
        Wt[(cq * 4 + 0) * PS + k] = f2bf(w.x);
        Wt[(cq * 4 + 1) * PS + k] = f2bf(w.y);
        Wt[(cq * 4 + 2) * PS + k] = f2bf(w.z);
        Wt[(cq * 4 + 3) * PS + k] = f2bf(w.w);
    }
    float bc = B[cb + colin];
    for (int tile = blockIdx.x; tile < ntiles; tile += gridDim.x) {
        __syncthreads();
        int node0 = tile << 6;
        for (int i = tid; i < DIN * 16; i += 256) {
            int flat = i << 2;
            int rr = flat / DIN, kk = flat % DIN;
            int gsrc = min(node0 + rr, n - 1);
            float4 v = *(const float4*)&X[(size_t)gsrc * DIN + kk];
            ushort4 u;
            u.x = f2bf(v.x);
            u.y = f2bf(v.y);
            u.z = f2bf(v.z);
            u.w = f2bf(v.w);
            *(ushort4*)&Xl[rr * PS + kk] = u;
        }
        __syncthreads();
        f32x4 acc[4];
#pragma unroll
        for (int rb = 0; rb < 4; rb++) acc[rb] = (f32x4){bc, bc, bc, bc};
#pragma unroll
        for (int ks = 0; ks < DIN; ks += 32) {
            bf16x8 bfr = *(const bf16x8*)&Wt[(cb + colin) * PS + ks + ksel * 8];
#pragma unroll
            for (int rb = 0; rb < 4; rb++) {
                bf16x8 afr = *(const bf16x8*)&Xl[(rb * 16 + colin) * PS + ks + ksel * 8];
                acc[rb] = __builtin_amdgcn_mfma_f32_16x16x32_bf16(afr, bfr, acc[rb], 0, 0, 0);
            }
        }
#pragma unroll
        for (int rb = 0; rb < 4; rb++) {
#pragma unroll
            for (int r = 0; r < 4; r++) {
                int node = node0 + rb * 16 + ksel * 4 + r;
                if (node < n) Hbf[(size_t)node * 64 + cb + colin] = f2bf(acc[rb][r]);
            }
        }
    }
}

// ---- alpha: AL[n] = h[n].al, AR[n] = h[n].ar from bf16 H (one wave/node) ----
__global__ __launch_bounds__(256) void alpha_kernel(const ushort* __restrict__ Hbf,
                                                    const float* __restrict__ attl,
                                                    const float* __restrict__ attr,
                                                    float* __restrict__ AL,
                                                    float* __restrict__ AR, int n) {
    int wv = threadIdx.x >> 6, lane = threadIdx.x & 63;
    int nd = blockIdx.x * 4 + wv;
    if (nd >= n) return;
    float h = bflo(Hbf[(size_t)nd * 64 + lane]);
    float pl = h * attl[lane], pr = h * attr[lane];
#pragma unroll
    for (int o = 32; o; o >>= 1) {
        pl += __shfl_xor(pl, o, 64);
        pr += __shfl_xor(pr, o, 64);
    }
    if (lane == 0) {
        AL[nd] = pl;
        AR[nd] = pr;
    }
}

// ---- One wave per dst node: raw-exp softmax + deep-prefetch gather ----
// exp(e)/sum(exp(e)) == exp(e-m)/sum(exp(e-m)); logits bounded (~|e|<3).
__global__ __launch_bounds__(256) void agg_kernel(const int* __restrict__ rowptr,
                                                  const int* __restrict__ col,
                                                  const float* __restrict__ AL,
                                                  const float* __restrict__ AR,
                                                  const ushort* __restrict__ Hbf,
                                                  float* __restrict__ OUT, int n) {
    int wv = threadIdx.x >> 6, lane = threadIdx.x & 63;
    int nidx = blockIdx.x * 4 + wv;
    if (nidx >= n) return;
    int beg = rowptr[nidx], end = rowptr[nidx + 1];
    int deg = end - beg;
    float ar_i = AR[nidx];
    int g = lane >> 4;
    unsigned int sub = (lane & 15) << 3;
    float a0 = 0.f, a1 = 0.f, a2 = 0.f, a3 = 0.f, aw = 0.f;

    if (deg <= 32) {
        // hot path (>99.98% of nodes): fully unrolled, 8 loads in flight
        int c0 = 0;
        float x0 = 0.f;
        if (lane < deg) {
            c0 = col[beg + lane];
            float t = AL[c0] + ar_i;
            t = t > 0.f ? t : NEG_SLOPE * t;
            x0 = __expf(t);
        }
        float wv_[8];
        int sv_[8];
#pragma unroll
        for (int t = 0; t < 8; t++) {
            int idx = t * 4 + g;  // groups partition the 32 edge slots
            wv_[t] = __shfl(x0, idx, 64);
            sv_[t] = __shfl(c0, idx, 64);
        }
        uint2 dv_[8];
#pragma unroll
        for (int t = 0; t < 8; t++)
            dv_[t] = *(const uint2*)((const char*)Hbf + ((((unsigned)sv_[t]) << 7) + sub));
#pragma unroll
        for (int t = 0; t < 8; t++) {
            a0 = fmaf(wv_[t], bflo(dv_[t].x), a0);
            a1 = fmaf(wv_[t], bfhi(dv_[t].x), a1);
            a2 = fmaf(wv_[t], bflo(dv_[t].y), a2);
            a3 = fmaf(wv_[t], bfhi(dv_[t].y), a3);
            aw += wv_[t];
        }
    } else {
        // generic path (rare)
        int c0 = 0;
        float x0 = 0.f;
        if (lane < deg) {
            c0 = col[beg + lane];
            float t = AL[c0] + ar_i;
            t = t > 0.f ? t : NEG_SLOPE * t;
            x0 = __expf(t);
        }
        int c1 = 0;
        float x1 = 0.f;
        if (64 + lane < deg) {
            c1 = col[beg + 64 + lane];
            float t = AL[c1] + ar_i;
            t = t > 0.f ? t : NEG_SLOPE * t;
            x1 = __expf(t);
        }
        int kend0 = deg < 64 ? deg : 64;
        for (int k = 0; k < kend0; k += 8) {
            int i0 = k + g, i1 = k + 4 + g;
            float w0 = __shfl(x0, i0, 64);
            int s0 = __shfl(c0, i0, 64);
            float w1 = __shfl(x0, i1, 64);
            int s1 = __shfl(c0, i1, 64);
            uint2 d0 = *(const uint2*)((const char*)Hbf + ((((unsigned)s0) << 7) + sub));
            uint2 d1 = *(const uint2*)((const char*)Hbf + ((((unsigned)s1) << 7) + sub));
            a0 = fmaf(w0, bflo(d0.x), a0);
            a1 = fmaf(w0, bfhi(d0.x), a1);
            a2 = fmaf(w0, bflo(d0.y), a2);
            a3 = fmaf(w0, bfhi(d0.y), a3);
            a0 = fmaf(w1, bflo(d1.x), a0);
            a1 = fmaf(w1, bfhi(d1.x), a1);
            a2 = fmaf(w1, bflo(d1.y), a2);
            a3 = fmaf(w1, bfhi(d1.y), a3);
            aw += w0 + w1;
        }
        if (deg > 64) {
            int kend1 = deg - 64 < 64 ? deg - 64 : 64;
            for (int k = 0; k < kend1; k += 8) {
                int i0 = k + g, i1 = k + 4 + g;
                float w0 = __shfl(x1, i0, 64);
                int s0 = __shfl(c1, i0, 64);
                float w1 = __shfl(x1, i1, 64);
                int s1 = __shfl(c1, i1, 64);
                uint2 d0 = *(const uint2*)((const char*)Hbf + ((((unsigned)s0) << 7) + sub));
                uint2 d1 = *(const uint2*)((const char*)Hbf + ((((unsigned)s1) << 7) + sub));
                a0 = fmaf(w0, bflo(d0.x), a0);
                a1 = fmaf(w0, bfhi(d0.x), a1);
                a2 = fmaf(w0, bflo(d0.y), a2);
                a3 = fmaf(w0, bfhi(d0.y), a3);
                a0 = fmaf(w1, bflo(d1.x), a0);
                a1 = fmaf(w1, bfhi(d1.x), a1);
                a2 = fmaf(w1, bflo(d1.y), a2);
                a3 = fmaf(w1, bfhi(d1.y), a3);
                aw += w0 + w1;
            }
            // cold path deg>128: groups partition edges (j step 4) so the
            // cross-group reduce doesn't double-count.
            for (int j = beg + 128 + g; j < end; j += 4) {
                int s = col[j];
                float t = AL[s] + ar_i;
                t = t > 0.f ? t : NEG_SLOPE * t;
                float ex = __expf(t);
                uint2 d = *(const uint2*)((const char*)Hbf + ((((unsigned)s) << 7) + sub));
                a0 = fmaf(ex, bflo(d.x), a0);
                a1 = fmaf(ex, bfhi(d.x), a1);
                a2 = fmaf(ex, bflo(d.y), a2);
                a3 = fmaf(ex, bfhi(d.y), a3);
                aw += ex;
            }
        }
    }
    // cross-group reduction: channels partials + denominator together
    a0 += __shfl_xor(a0, 16, 64);
    a0 += __shfl_xor(a0, 32, 64);
    a1 += __shfl_xor(a1, 16, 64);
    a1 += __shfl_xor(a1, 32, 64);
    a2 += __shfl_xor(a2, 16, 64);
    a2 += __shfl_xor(a2, 32, 64);
    a3 += __shfl_xor(a3, 16, 64);
    a3 += __shfl_xor(a3, 32, 64);
    aw += __shfl_xor(aw, 16, 64);
    aw += __shfl_xor(aw, 32, 64);
    if (g == 0) {
        float r = 1.0f / (aw + EPS);
        float o0 = a0 * r, o1 = a1 * r, o2 = a2 * r, o3 = a3 * r;
        o0 = o0 > 0.f ? o0 : 0.f;
        o1 = o1 > 0.f ? o1 : 0.f;
        o2 = o2 > 0.f ? o2 : 0.f;
        o3 = o3 > 0.f ? o3 : 0.f;
        *(float4*)((char*)OUT + (((size_t)nidx) << 8) + (sub << 1)) =
            make_float4(o0, o1, o2, o3);
    }
}

// ---- MFMA post: q = (h3@W1+b1)@W2+b2 ; log_softmax ----
__global__ __launch_bounds__(256) void post_mfma_kernel(const float* __restrict__ H3,
                                                        const float* __restrict__ Wp1,
                                                        const float* __restrict__ bp1,
                                                        const float* __restrict__ Wp2,
                                                        const float* __restrict__ bp2,
                                                        float* __restrict__ OUT,
                                                        int n, int ntiles) {
    constexpr int PS = 72;
    __shared__ ushort Hl[64 * PS];
    __shared__ ushort Pl[64 * PS];
    __shared__ ushort Wt1[64 * PS];
    __shared__ ushort Wt2[64 * PS];
    __shared__ float Ql[64 * PS];
    int tid = threadIdx.x;
    int lane = tid & 63;
    int cb = (tid >> 6) << 4;
    int colin = lane & 15, ksel = lane >> 4;
    for (int i = tid; i < 64 * 16; i += 256) {
        int k = i >> 4, cq = i & 15;
        float4 w1 = *(const float4*)&Wp1[k * 64 + cq * 4];
        Wt1[(cq * 4 + 0) * PS + k] = f2bf(w1.x);
        Wt1[(cq * 4 + 1) * PS + k] = f2bf(w1.y);
        Wt1[(cq * 4 + 2) * PS + k] = f2bf(w1.z);
        Wt1[(cq * 4 + 3) * PS + k] = f2bf(w1.w);
#pragma unroll
        for (int j = 0; j < 4; j++) {
            int c = cq * 4 + j;
            float w2 = (c < OUT_DIM) ? Wp2[k * OUT_DIM + c] : 0.f;
            Wt2[c * PS + k] = f2bf(w2);
        }
    }
    int myc = cb + colin;
    float bc1 = bp1[myc];
    float bc2 = (myc < OUT_DIM) ? bp2[myc] : 0.f;
    for (int tile = blockIdx.x; tile < ntiles; tile += gridDim.x) {
        __syncthreads();
        int node0 = tile << 6;
        for (int i = tid; i < 64 * 16; i += 256) {
            int flat = i << 2;
            int rr = flat >> 6, kk = flat & 63;
            int gsrc = min(node0 + rr, n - 1);
            float4 v = *(const float4*)&H3[(size_t)gsrc * 64 + kk];
            ushort4 u;
            u.x = f2bf(v.x);
            u.y = f2bf(v.y);
            u.z = f2bf(v.z);
            u.w = f2bf(v.w);
            *(ushort4*)&Hl[rr * PS + kk] = u;
        }
        __syncthreads();
        f32x4 acc1[4];
#pragma unroll
        for (int rb = 0; rb < 4; rb++) acc1[rb] = (f32x4){bc1, bc1, bc1, bc1};
#pragma unroll
        for (int ks = 0; ks < 64; ks += 32) {
            bf16x8 bfr = *(const bf16x8*)&Wt1[myc * PS + ks + ksel * 8];
#pragma unroll
            for (int rb = 0; rb < 4; rb++) {
                bf16x8 afr = *(const bf16x8*)&Hl[(rb * 16 + colin) * PS + ks + ksel * 8];
                acc1[rb] = __builtin_amdgcn_mfma_f32_16x16x32_bf16(afr, bfr, acc1[rb], 0, 0, 0);
            }
        }
#pragma unroll
        for (int rb = 0; rb < 4; rb++) {
#pragma unroll
            for (int r = 0; r < 4; r++) {
                int row = rb * 16 + ksel * 4 + r;
                Pl[row * PS + myc] = f2bf(acc1[rb][r]);
            }
        }
        __syncthreads();
        f32x4 acc2[4];
#pragma unroll
        for (int rb = 0; rb < 4; rb++) acc2[rb] = (f32x4){bc2, bc2, bc2, bc2};
#pragma unroll
        for (int ks = 0; ks < 64; ks += 32) {
            bf16x8 bfr = *(const bf16x8*)&Wt2[myc * PS + ks + ksel * 8];
#pragma unroll
            for (int rb = 0; rb < 4; rb++) {
                bf16x8 afr = *(const bf16x8*)&Pl[(rb * 16 + colin) * PS + ks + ksel * 8];
                acc2[rb] = __builtin_amdgcn_mfma_f32_16x16x32_bf16(afr, bfr, acc2[rb], 0, 0, 0);
            }
        }
#pragma unroll
        for (int rb = 0; rb < 4; rb++) {
#pragma unroll
            for (int r = 0; r < 4; r++) {
                int row = rb * 16 + ksel * 4 + r;
                Ql[row * PS + myc] = acc2[rb][r];
            }
        }
        __syncthreads();
        int nd = tid >> 2, part = tid & 3;
        int cbeg = part * 12;
        float m = -INFINITY;
#pragma unroll
        for (int i = 0; i < 12; i++) {
            int c = cbeg + i;
            if (c < OUT_DIM) m = fmaxf(m, Ql[nd * PS + c]);
        }
        m = fmaxf(m, __shfl_xor(m, 1, 64));
        m = fmaxf(m, __shfl_xor(m, 2, 64));
        float s = 0.f;
#pragma unroll
        for (int i = 0; i < 12; i++) {
            int c = cbeg + i;
            if (c < OUT_DIM) s += __expf(Ql[nd * PS + c] - m);
        }
        s += __shfl_xor(s, 1, 64);
        s += __shfl_xor(s, 2, 64);
        float lg = m + __logf(s);
        int node = node0 + nd;
        if (node < n) {
#pragma unroll
            for (int i = 0; i < 12; i++) {
                int c = cbeg + i;
                if (c < OUT_DIM) OUT[(size_t)node * OUT_DIM + c] = Ql[nd * PS + c] - lg;
            }
        }
    }
}

extern "C" void kernel_launch(void* const* d_in, const int* in_sizes, int n_in,
                              void* d_out, int out_size, void* d_ws, size_t ws_size,
                              hipStream_t stream) {
    const float* x = (const float*)d_in[0];
    const int* ei = (const int*)d_in[1];
    const float* W0 = (const float*)d_in[2];
    const float* b0 = (const float*)d_in[3];
    const float* al0 = (const float*)d_in[4];
    const float* ar0 = (const float*)d_in[5];
    const float* W1 = (const float*)d_in[6];
    const float* b1 = (const float*)d_in[7];
    const float* al1 = (const float*)d_in[8];
    const float* ar1 = (const float*)d_in[9];
    const float* W2 = (const float*)d_in[10];
    const float* b2 = (const float*)d_in[11];
    const float* al2 = (const float*)d_in[12];
    const float* ar2 = (const float*)d_in[13];
    const float* Wp1 = (const float*)d_in[14];
    const float* bp1 = (const float*)d_in[15];
    const float* Wp2 = (const float*)d_in[16];
    const float* bp2 = (const float*)d_in[17];
    float* out = (float*)d_out;

    const int N = in_sizes[0] / IN_DIM;
    const int E = in_sizes[1] / 2;
    const int NBUCK = (N + BN - 1) >> BBITS;
    const int NTILES = (N + 63) >> 6;

    char* ws = (char*)d_ws;
    float* Hf = (float*)ws;      ws += (size_t)N * 64 * sizeof(float);
    ushort* Hbf = (ushort*)ws;   ws += (size_t)N * 64 * sizeof(ushort);
    float* ALb = (float*)ws;     ws += (size_t)N * sizeof(float);
    float* ARb = (float*)ws;     ws += (size_t)N * sizeof(float);
    int* rowptr = (int*)ws;      ws += (size_t)(N + 1) * sizeof(int);
    int* col = (int*)ws;         ws += (size_t)E * sizeof(int);
    int* bcnt = (int*)ws;        ws += (size_t)NBUCK * sizeof(int);
    int* bbase = (int*)ws;       ws += (size_t)(NBUCK + 1) * sizeof(int);
    int* bfill = (int*)ws;       ws += (size_t)NBUCK * sizeof(int);
    int2* stg = (int2*)Hf;  // staging aliases Hf (dead until agg0 writes it)

    const int* src = ei;
    const int* dst = ei + E;

    hipMemsetAsync(bcnt, 0, (size_t)NBUCK * sizeof(int), stream);
    bucket_count_kernel<<<256, 256, 0, stream>>>(dst, bcnt, E, NBUCK);
    bucket_scan_kernel<<<1, 64, 0, stream>>>(bcnt, bbase, bfill, NBUCK);
    bucket_scatter_kernel<<<256, 256, 0, stream>>>(src, dst, bfill, stg, E, NBUCK);
    bucket_place_kernel<<<NBUCK, 1024, 0, stream>>>(stg, bbase, rowptr, col, N, E);

    int agg_grid = (N + 3) / 4;
    int alpha_grid = (N + 3) / 4;

    // ---- layer 0 ----
    lin_mfma_kernel<IN_DIM><<<512, 256, 0, stream>>>(x, W0, b0, Hbf, N, NTILES);
    alpha_kernel<<<alpha_grid, 256, 0, stream>>>(Hbf, al0, ar0, ALb, ARb, N);
    agg_kernel<<<agg_grid, 256, 0, stream>>>(rowptr, col, ALb, ARb, Hbf, Hf, N);
    // ---- layer 1 ----
    lin_mfma_kernel<HID><<<512, 256, 0, stream>>>(Hf, W1, b1, Hbf, N, NTILES);
    alpha_kernel<<<alpha_grid, 256, 0, stream>>>(Hbf, al1, ar1, ALb, ARb, N);
    agg_kernel<<<agg_grid, 256, 0, stream>>>(rowptr, col, ALb, ARb, Hbf, Hf, N);
    // ---- layer 2 ----
    lin_mfma_kernel<HID><<<512, 256, 0, stream>>>(Hf, W2, b2, Hbf, N, NTILES);
    alpha_kernel<<<alpha_grid, 256, 0, stream>>>(Hbf, al2, ar2, ALb, ARb, N);
    agg_kernel<<<agg_grid, 256, 0, stream>>>(rowptr, col, ALb, ARb, Hbf, Hf, N);
    // ---- post ----
    post_mfma_kernel<<<512, 256, 0, stream>>>(Hf, Wp1, bp1, Wp2, bp2, out, N, NTILES);
}

// Round 9
// 293.616 us; speedup vs baseline: 1.3450x; 1.0463x over previous
//
#include <hip/hip_runtime.h>
#include <hip/hip_bf16.h>
#include <math.h>

// GNNStack: 3x GAT(heads=1, hid=64) + relu, then 64->64, 64->47, log_softmax.
//  - CSR build via two-level counting sort (no per-node global atomics).
//  - LIN: MFMA 16x16x32 bf16 with FUSED alpha dots (shfl-reduce epilogue).
//  - All inter-layer tensors bf16 (agg writes bf16 directly; GEMMs staged
//    to bf16 anyway -> bit-identical GEMM inputs, less traffic).
//  - AGG R9: degree-adaptive hot path — two 4-step halves, second skipped
//    when deg<=16 (wave-uniform); raw-exp softmax (shift-invariant, logits
//    bounded); denom folded into cross-group reduction.

#define IN_DIM 128
#define HID 64
#define OUT_DIM 47
#define NEG_SLOPE 0.2f
#define EPS 1e-16f
#define BBITS 10
#define BN 1024
#define NBUCK_MAX 128

typedef short bf16x8 __attribute__((ext_vector_type(8)));
typedef float f32x4 __attribute__((ext_vector_type(4)));

__device__ __forceinline__ float bflo(unsigned int d) {
    union { unsigned int i; float f; } c;
    c.i = d << 16;
    return c.f;
}
__device__ __forceinline__ float bfhi(unsigned int d) {
    union { unsigned int i; float f; } c;
    c.i = d & 0xffff0000u;
    return c.f;
}
__device__ __forceinline__ ushort f2bf(float f) {
    __hip_bfloat16 b = __float2bfloat16(f);
    return *(ushort*)&b;
}

// ---- CSR build ----
__global__ __launch_bounds__(256) void bucket_count_kernel(const int* __restrict__ dst,
                                                           int* __restrict__ bcnt,
                                                           int e, int nbuck) {
    __shared__ int h[NBUCK_MAX];
    int tid = threadIdx.x;
    if (tid < nbuck) h[tid] = 0;
    __syncthreads();
    int chunk = (e + gridDim.x - 1) / gridDim.x;
    int beg = blockIdx.x * chunk, end = min(e, beg + chunk);
    for (int i = beg + tid; i < end; i += 256) atomicAdd(&h[dst[i] >> BBITS], 1);
    __syncthreads();
    if (tid < nbuck && h[tid]) atomicAdd(&bcnt[tid], h[tid]);
}

__global__ void bucket_scan_kernel(const int* __restrict__ bcnt, int* __restrict__ bbase,
                                   int* __restrict__ bfill, int nbuck) {
    if (threadIdx.x == 0 && blockIdx.x == 0) {
        int run = 0;
        for (int i = 0; i < nbuck; i++) { bbase[i] = run; bfill[i] = run; run += bcnt[i]; }
        bbase[nbuck] = run;
    }
}

__global__ __launch_bounds__(256) void bucket_scatter_kernel(const int* __restrict__ src,
                                                             const int* __restrict__ dst,
                                                             int* __restrict__ bfill,
                                                             int2* __restrict__ stg,
                                                             int e, int nbuck) {
    __shared__ int lcnt[NBUCK_MAX], lfill[NBUCK_MAX];
    int tid = threadIdx.x;
    if (tid < nbuck) lcnt[tid] = 0;
    __syncthreads();
    int chunk = (e + gridDim.x - 1) / gridDim.x;
    int beg = blockIdx.x * chunk, end = min(e, beg + chunk);
    for (int i = beg + tid; i < end; i += 256) atomicAdd(&lcnt[dst[i] >> BBITS], 1);
    __syncthreads();
    if (tid < nbuck) lfill[tid] = lcnt[tid] ? atomicAdd(&bfill[tid], lcnt[tid]) : 0;
    __syncthreads();
    for (int i = beg + tid; i < end; i += 256) {
        int d = dst[i];
        int p = atomicAdd(&lfill[d >> BBITS], 1);
        stg[p] = make_int2(src[i], d);
    }
}

__global__ __launch_bounds__(1024) void bucket_place_kernel(const int2* __restrict__ stg,
                                                            const int* __restrict__ bbase,
                                                            int* __restrict__ rowptr,
                                                            int* __restrict__ col,
                                                            int n, int e) {
    __shared__ int lcnt[BN];
    __shared__ int lscan[BN];
    __shared__ int lfill[BN];
    int tid = threadIdx.x, b = blockIdx.x;
    int node0 = b << BBITS;
    int ebeg = bbase[b], eend = bbase[b + 1];
    lcnt[tid] = 0;
    __syncthreads();
    for (int j = ebeg + tid; j < eend; j += 1024) atomicAdd(&lcnt[stg[j].y - node0], 1);
    __syncthreads();
    int v = lcnt[tid];
    lscan[tid] = v;
    __syncthreads();
    for (int off = 1; off < 1024; off <<= 1) {
        int t = (tid >= off) ? lscan[tid - off] : 0;
        __syncthreads();
        lscan[tid] += t;
        __syncthreads();
    }
    int gbase = ebeg + lscan[tid] - v;
    if (node0 + tid < n) rowptr[node0 + tid] = gbase;
    lfill[tid] = gbase;
    __syncthreads();
    for (int j = ebeg + tid; j < eend; j += 1024) {
        int2 ed = stg[j];
        int p = atomicAdd(&lfill[ed.y - node0], 1);
        col[p] = ed.x;
    }
    if (b == 0 && tid == 0) rowptr[n] = e;
}

// ---- MFMA lin + fused alpha: H = bf16(X@W+b); AL/AR = H.attl/attr ----
template <int DIN, bool BF16IN>
__global__ __launch_bounds__(256) void lin_mfma_kernel(const void* __restrict__ Xin,
                                                       const float* __restrict__ W,
                                                       const float* __restrict__ B,
                                                       const float* __restrict__ attl,
                                                       const float* __restrict__ attr,
                                                       ushort* __restrict__ Hbf,
                                                       float* __restrict__ AL,
                                                       float* __restrict__ AR,
                                                       int n, int ntiles) {
    constexpr int PS = DIN + 8;
    __shared__ ushort Xl[64 * PS];
    __shared__ ushort Wt[64 * PS];  // Wt[c][k] = W[k][c]
    __shared__ float redl[4][64], redr[4][64];
    int tid = threadIdx.x;
    int lane = tid & 63;
    int wvi = tid >> 6;
    int cb = wvi << 4;
    int colin = lane & 15, ksel = lane >> 4;
    for (int i = tid; i < DIN * 16; i += 256) {
        int k = i >> 4, cq = i & 15;
        float4 w = *(const float4*)&W[k * 64 + cq * 4];
        Wt[(cq * 4 + 0) * PS + k] = f2bf(w.x);
        Wt[(cq * 4 + 1) * PS + k] = f2bf(w.y);
        Wt[(cq * 4 + 2) * PS + k] = f2bf(w.z);
        Wt[(cq * 4 + 3) * PS + k] = f2bf(w.w);
    }
    float bc = B[cb + colin];
    float al_c = attl[cb + colin], ar_c = attr[cb + colin];
    for (int tile = blockIdx.x; tile < ntiles; tile += gridDim.x) {
        __syncthreads();  // guards Xl restage + redl reuse (and initial Wt)
        int node0 = tile << 6;
        if constexpr (BF16IN) {
            const ushort* Xb = (const ushort*)Xin;
            for (int i = tid; i < 64 * DIN / 8; i += 256) {
                int rr = i / (DIN / 8), ck = (i % (DIN / 8)) * 8;
                int gsrc = min(node0 + rr, n - 1);
                *(uint4*)&Xl[rr * PS + ck] = *(const uint4*)&Xb[(size_t)gsrc * DIN + ck];
            }
        } else {
            const float* Xf = (const float*)Xin;
            for (int i = tid; i < DIN * 16; i += 256) {
                int flat = i << 2;
                int rr = flat / DIN, kk = flat % DIN;
                int gsrc = min(node0 + rr, n - 1);
                float4 v = *(const float4*)&Xf[(size_t)gsrc * DIN + kk];
                ushort4 u;
                u.x = f2bf(v.x);
                u.y = f2bf(v.y);
                u.z = f2bf(v.z);
                u.w = f2bf(v.w);
                *(ushort4*)&Xl[rr * PS + kk] = u;
            }
        }
        __syncthreads();
        f32x4 acc[4];
#pragma unroll
        for (int rb = 0; rb < 4; rb++) acc[rb] = (f32x4){bc, bc, bc, bc};
#pragma unroll
        for (int ks = 0; ks < DIN; ks += 32) {
            bf16x8 bfr = *(const bf16x8*)&Wt[(cb + colin) * PS + ks + ksel * 8];
#pragma unroll
            for (int rb = 0; rb < 4; rb++) {
                bf16x8 afr = *(const bf16x8*)&Xl[(rb * 16 + colin) * PS + ks + ksel * 8];
                acc[rb] = __builtin_amdgcn_mfma_f32_16x16x32_bf16(afr, bfr, acc[rb], 0, 0, 0);
            }
        }
        // H store (D layout: col = cb+colin, row = rb*16 + ksel*4 + r)
#pragma unroll
        for (int rb = 0; rb < 4; rb++) {
#pragma unroll
            for (int r = 0; r < 4; r++) {
                int node = node0 + rb * 16 + ksel * 4 + r;
                if (node < n) Hbf[(size_t)node * 64 + cb + colin] = f2bf(acc[rb][r]);
            }
        }
        // fused alpha: reduce acc*att over the 16-lane colin group per row
#pragma unroll
        for (int rb = 0; rb < 4; rb++) {
#pragma unroll
            for (int r = 0; r < 4; r++) {
                float pl = acc[rb][r] * al_c;
                float pr = acc[rb][r] * ar_c;
#pragma unroll
                for (int o = 1; o < 16; o <<= 1) {
                    pl += __shfl_xor(pl, o, 64);
                    pr += __shfl_xor(pr, o, 64);
                }
                if (colin == 0) {
                    int row = rb * 16 + ksel * 4 + r;
                    redl[wvi][row] = pl;
                    redr[wvi][row] = pr;
                }
            }
        }
        __syncthreads();
        if (tid < 64) {
            int node = node0 + tid;
            if (node < n) {
                AL[node] = redl[0][tid] + redl[1][tid] + redl[2][tid] + redl[3][tid];
                AR[node] = redr[0][tid] + redr[1][tid] + redr[2][tid] + redr[3][tid];
            }
        }
    }
}

// ---- One wave per dst node: raw-exp softmax + degree-adaptive gather ----
__global__ __launch_bounds__(256) void agg_kernel(const int* __restrict__ rowptr,
                                                  const int* __restrict__ col,
                                                  const float* __restrict__ AL,
                                                  const float* __restrict__ AR,
                                                  const ushort* __restrict__ Hbf,
                                                  ushort* __restrict__ OUT, int n) {
    int wv = threadIdx.x >> 6, lane = threadIdx.x & 63;
    int nidx = blockIdx.x * 4 + wv;
    if (nidx >= n) return;
    int beg = rowptr[nidx], end = rowptr[nidx + 1];
    int deg = end - beg;
    float ar_i = AR[nidx];
    int g = lane >> 4;
    unsigned int sub = (lane & 15) << 3;
    float a0 = 0.f, a1 = 0.f, a2 = 0.f, a3 = 0.f, aw = 0.f;

    if (deg <= 32) {
        int c0 = 0;
        float x0 = 0.f;
        if (lane < deg) {
            c0 = col[beg + lane];
            float t = AL[c0] + ar_i;
            t = t > 0.f ? t : NEG_SLOPE * t;
            x0 = __expf(t);
        }
        // half A: slots 0..15 (always)
        {
            float w_[4];
            int s_[4];
#pragma unroll
            for (int t = 0; t < 4; t++) {
                int idx = t * 4 + g;
                w_[t] = __shfl(x0, idx, 64);
                s_[t] = __shfl(c0, idx, 64);
            }
            uint2 d_[4];
#pragma unroll
            for (int t = 0; t < 4; t++)
                d_[t] = *(const uint2*)((const char*)Hbf + ((((unsigned)s_[t]) << 7) + sub));
#pragma unroll
            for (int t = 0; t < 4; t++) {
                a0 = fmaf(w_[t], bflo(d_[t].x), a0);
                a1 = fmaf(w_[t], bfhi(d_[t].x), a1);
                a2 = fmaf(w_[t], bflo(d_[t].y), a2);
                a3 = fmaf(w_[t], bfhi(d_[t].y), a3);
                aw += w_[t];
            }
        }
        if (deg > 16) {  // half B: slots 16..31 (wave-uniform skip)
            float w_[4];
            int s_[4];
#pragma unroll
            for (int t = 0; t < 4; t++) {
                int idx = 16 + t * 4 + g;
                w_[t] = __shfl(x0, idx, 64);
                s_[t] = __shfl(c0, idx, 64);
            }
            uint2 d_[4];
#pragma unroll
            for (int t = 0; t < 4; t++)
                d_[t] = *(const uint2*)((const char*)Hbf + ((((unsigned)s_[t]) << 7) + sub));
#pragma unroll
            for (int t = 0; t < 4; t++) {
                a0 = fmaf(w_[t], bflo(d_[t].x), a0);
                a1 = fmaf(w_[t], bfhi(d_[t].x), a1);
                a2 = fmaf(w_[t], bflo(d_[t].y), a2);
                a3 = fmaf(w_[t], bfhi(d_[t].y), a3);
                aw += w_[t];
            }
        }
    } else {
        // generic path (rare, deg>32)
        int c0 = 0;
        float x0 = 0.f;
        if (lane < deg) {
            c0 = col[beg + lane];
            float t = AL[c0] + ar_i;
            t = t > 0.f ? t : NEG_SLOPE * t;
            x0 = __expf(t);
        }
        int c1 = 0;
        float x1 = 0.f;
        if (64 + lane < deg) {
            c1 = col[beg + 64 + lane];
            float t = AL[c1] + ar_i;
            t = t > 0.f ? t : NEG_SLOPE * t;
            x1 = __expf(t);
        }
        int kend0 = deg < 64 ? deg : 64;
        for (int k = 0; k < kend0; k += 8) {
            int i0 = k + g, i1 = k + 4 + g;
            float w0 = __shfl(x0, i0, 64);
            int s0 = __shfl(c0, i0, 64);
            float w1 = __shfl(x0, i1, 64);
            int s1 = __shfl(c0, i1, 64);
            uint2 d0 = *(const uint2*)((const char*)Hbf + ((((unsigned)s0) << 7) + sub));
            uint2 d1 = *(const uint2*)((const char*)Hbf + ((((unsigned)s1) << 7) + sub));
            a0 = fmaf(w0, bflo(d0.x), a0);
            a1 = fmaf(w0, bfhi(d0.x), a1);
            a2 = fmaf(w0, bflo(d0.y), a2);
            a3 = fmaf(w0, bfhi(d0.y), a3);
            a0 = fmaf(w1, bflo(d1.x), a0);
            a1 = fmaf(w1, bfhi(d1.x), a1);
            a2 = fmaf(w1, bflo(d1.y), a2);
            a3 = fmaf(w1, bfhi(d1.y), a3);
            aw += w0 + w1;
        }
        if (deg > 64) {
            int kend1 = deg - 64 < 64 ? deg - 64 : 64;
            for (int k = 0; k < kend1; k += 8) {
                int i0 = k + g, i1 = k + 4 + g;
                float w0 = __shfl(x1, i0, 64);
                int s0 = __shfl(c1, i0, 64);
                float w1 = __shfl(x1, i1, 64);
                int s1 = __shfl(c1, i1, 64);
                uint2 d0 = *(const uint2*)((const char*)Hbf + ((((unsigned)s0) << 7) + sub));
                uint2 d1 = *(const uint2*)((const char*)Hbf + ((((unsigned)s1) << 7) + sub));
                a0 = fmaf(w0, bflo(d0.x), a0);
                a1 = fmaf(w0, bfhi(d0.x), a1);
                a2 = fmaf(w0, bflo(d0.y), a2);
                a3 = fmaf(w0, bfhi(d0.y), a3);
                a0 = fmaf(w1, bflo(d1.x), a0);
                a1 = fmaf(w1, bfhi(d1.x), a1);
                a2 = fmaf(w1, bflo(d1.y), a2);
                a3 = fmaf(w1, bfhi(d1.y), a3);
                aw += w0 + w1;
            }
            for (int j = beg + 128 + g; j < end; j += 4) {  // groups partition
                int s = col[j];
                float t = AL[s] + ar_i;
                t = t > 0.f ? t : NEG_SLOPE * t;
                float ex = __expf(t);
                uint2 d = *(const uint2*)((const char*)Hbf + ((((unsigned)s) << 7) + sub));
                a0 = fmaf(ex, bflo(d.x), a0);
                a1 = fmaf(ex, bfhi(d.x), a1);
                a2 = fmaf(ex, bflo(d.y), a2);
                a3 = fmaf(ex, bfhi(d.y), a3);
                aw += ex;
            }
        }
    }
    a0 += __shfl_xor(a0, 16, 64);
    a0 += __shfl_xor(a0, 32, 64);
    a1 += __shfl_xor(a1, 16, 64);
    a1 += __shfl_xor(a1, 32, 64);
    a2 += __shfl_xor(a2, 16, 64);
    a2 += __shfl_xor(a2, 32, 64);
    a3 += __shfl_xor(a3, 16, 64);
    a3 += __shfl_xor(a3, 32, 64);
    aw += __shfl_xor(aw, 16, 64);
    aw += __shfl_xor(aw, 32, 64);
    if (g == 0) {
        float r = 1.0f / (aw + EPS);
        float o0 = a0 * r, o1 = a1 * r, o2 = a2 * r, o3 = a3 * r;
        o0 = o0 > 0.f ? o0 : 0.f;
        o1 = o1 > 0.f ? o1 : 0.f;
        o2 = o2 > 0.f ? o2 : 0.f;
        o3 = o3 > 0.f ? o3 : 0.f;
        uint2 o;
        o.x = (unsigned int)f2bf(o0) | ((unsigned int)f2bf(o1) << 16);
        o.y = (unsigned int)f2bf(o2) | ((unsigned int)f2bf(o3) << 16);
        *(uint2*)((char*)OUT + (((size_t)nidx) << 7) + sub) = o;
    }
}

// ---- MFMA post (bf16 input): q = (h3@W1+b1)@W2+b2 ; log_softmax ----
__global__ __launch_bounds__(256) void post_mfma_kernel(const ushort* __restrict__ H3,
                                                        const float* __restrict__ Wp1,
                                                        const float* __restrict__ bp1,
                                                        const float* __restrict__ Wp2,
                                                        const float* __restrict__ bp2,
                                                        float* __restrict__ OUT,
                                                        int n, int ntiles) {
    constexpr int PS = 72;
    __shared__ ushort Hl[64 * PS];
    __shared__ ushort Pl[64 * PS];
    __shared__ ushort Wt1[64 * PS];
    __shared__ ushort Wt2[64 * PS];
    __shared__ float Ql[64 * PS];
    int tid = threadIdx.x;
    int lane = tid & 63;
    int cb = (tid >> 6) << 4;
    int colin = lane & 15, ksel = lane >> 4;
    for (int i = tid; i < 64 * 16; i += 256) {
        int k = i >> 4, cq = i & 15;
        float4 w1 = *(const float4*)&Wp1[k * 64 + cq * 4];
        Wt1[(cq * 4 + 0) * PS + k] = f2bf(w1.x);
        Wt1[(cq * 4 + 1) * PS + k] = f2bf(w1.y);
        Wt1[(cq * 4 + 2) * PS + k] = f2bf(w1.z);
        Wt1[(cq * 4 + 3) * PS + k] = f2bf(w1.w);
#pragma unroll
        for (int j = 0; j < 4; j++) {
            int c = cq * 4 + j;
            float w2 = (c < OUT_DIM) ? Wp2[k * OUT_DIM + c] : 0.f;
            Wt2[c * PS + k] = f2bf(w2);
        }
    }
    int myc = cb + colin;
    float bc1 = bp1[myc];
    float bc2 = (myc < OUT_DIM) ? bp2[myc] : 0.f;
    for (int tile = blockIdx.x; tile < ntiles; tile += gridDim.x) {
        __syncthreads();
        int node0 = tile << 6;
        for (int i = tid; i < 64 * 8; i += 256) {
            int rr = i >> 3, ck = (i & 7) << 3;
            int gsrc = min(node0 + rr, n - 1);
            *(uint4*)&Hl[rr * PS + ck] = *(const uint4*)&H3[(size_t)gsrc * 64 + ck];
        }
        __syncthreads();
        f32x4 acc1[4];
#pragma unroll
        for (int rb = 0; rb < 4; rb++) acc1[rb] = (f32x4){bc1, bc1, bc1, bc1};
#pragma unroll
        for (int ks = 0; ks < 64; ks += 32) {
            bf16x8 bfr = *(const bf16x8*)&Wt1[myc * PS + ks + ksel * 8];
#pragma unroll
            for (int rb = 0; rb < 4; rb++) {
                bf16x8 afr = *(const bf16x8*)&Hl[(rb * 16 + colin) * PS + ks + ksel * 8];
                acc1[rb] = __builtin_amdgcn_mfma_f32_16x16x32_bf16(afr, bfr, acc1[rb], 0, 0, 0);
            }
        }
#pragma unroll
        for (int rb = 0; rb < 4; rb++) {
#pragma unroll
            for (int r = 0; r < 4; r++) {
                int row = rb * 16 + ksel * 4 + r;
                Pl[row * PS + myc] = f2bf(acc1[rb][r]);
            }
        }
        __syncthreads();
        f32x4 acc2[4];
#pragma unroll
        for (int rb = 0; rb < 4; rb++) acc2[rb] = (f32x4){bc2, bc2, bc2, bc2};
#pragma unroll
        for (int ks = 0; ks < 64; ks += 32) {
            bf16x8 bfr = *(const bf16x8*)&Wt2[myc * PS + ks + ksel * 8];
#pragma unroll
            for (int rb = 0; rb < 4; rb++) {
                bf16x8 afr = *(const bf16x8*)&Pl[(rb * 16 + colin) * PS + ks + ksel * 8];
                acc2[rb] = __builtin_amdgcn_mfma_f32_16x16x32_bf16(afr, bfr, acc2[rb], 0, 0, 0);
            }
        }
#pragma unroll
        for (int rb = 0; rb < 4; rb++) {
#pragma unroll
            for (int r = 0; r < 4; r++) {
                int row = rb * 16 + ksel * 4 + r;
                Ql[row * PS + myc] = acc2[rb][r];
            }
        }
        __syncthreads();
        int nd = tid >> 2, part = tid & 3;
        int cbeg = part * 12;
        float m = -INFINITY;
#pragma unroll
        for (int i = 0; i < 12; i++) {
            int c = cbeg + i;
            if (c < OUT_DIM) m = fmaxf(m, Ql[nd * PS + c]);
        }
        m = fmaxf(m, __shfl_xor(m, 1, 64));
        m = fmaxf(m, __shfl_xor(m, 2, 64));
        float s = 0.f;
#pragma unroll
        for (int i = 0; i < 12; i++) {
            int c = cbeg + i;
            if (c < OUT_DIM) s += __expf(Ql[nd * PS + c] - m);
        }
        s += __shfl_xor(s, 1, 64);
        s += __shfl_xor(s, 2, 64);
        float lg = m + __logf(s);
        int node = node0 + nd;
        if (node < n) {
#pragma unroll
            for (int i = 0; i < 12; i++) {
                int c = cbeg + i;
                if (c < OUT_DIM) OUT[(size_t)node * OUT_DIM + c] = Ql[nd * PS + c] - lg;
            }
        }
    }
}

extern "C" void kernel_launch(void* const* d_in, const int* in_sizes, int n_in,
                              void* d_out, int out_size, void* d_ws, size_t ws_size,
                              hipStream_t stream) {
    const float* x = (const float*)d_in[0];
    const int* ei = (const int*)d_in[1];
    const float* W0 = (const float*)d_in[2];
    const float* b0 = (const float*)d_in[3];
    const float* al0 = (const float*)d_in[4];
    const float* ar0 = (const float*)d_in[5];
    const float* W1 = (const float*)d_in[6];
    const float* b1 = (const float*)d_in[7];
    const float* al1 = (const float*)d_in[8];
    const float* ar1 = (const float*)d_in[9];
    const float* W2 = (const float*)d_in[10];
    const float* b2 = (const float*)d_in[11];
    const float* al2 = (const float*)d_in[12];
    const float* ar2 = (const float*)d_in[13];
    const float* Wp1 = (const float*)d_in[14];
    const float* bp1 = (const float*)d_in[15];
    const float* Wp2 = (const float*)d_in[16];
    const float* bp2 = (const float*)d_in[17];
    float* out = (float*)d_out;

    const int N = in_sizes[0] / IN_DIM;
    const int E = in_sizes[1] / 2;
    const int NBUCK = (N + BN - 1) >> BBITS;
    const int NTILES = (N + 63) >> 6;

    char* ws = (char*)d_ws;
    ushort* HbfA = (ushort*)ws;  ws += (size_t)N * 64 * sizeof(ushort);  // lin out / agg in
    ushort* HbfB = (ushort*)ws;  ws += (size_t)N * 64 * sizeof(ushort);  // agg out / lin in
    float* ALb = (float*)ws;     ws += (size_t)N * sizeof(float);
    float* ARb = (float*)ws;     ws += (size_t)N * sizeof(float);
    int* rowptr = (int*)ws;      ws += (size_t)(N + 1) * sizeof(int);
    int* col = (int*)ws;         ws += (size_t)E * sizeof(int);
    int* bcnt = (int*)ws;        ws += (size_t)NBUCK * sizeof(int);
    int* bbase = (int*)ws;       ws += (size_t)(NBUCK + 1) * sizeof(int);
    int* bfill = (int*)ws;       ws += (size_t)NBUCK * sizeof(int);
    int2* stg = (int2*)ws;       ws += (size_t)E * sizeof(int2);

    const int* src = ei;
    const int* dst = ei + E;

    hipMemsetAsync(bcnt, 0, (size_t)NBUCK * sizeof(int), stream);
    bucket_count_kernel<<<256, 256, 0, stream>>>(dst, bcnt, E, NBUCK);
    bucket_scan_kernel<<<1, 64, 0, stream>>>(bcnt, bbase, bfill, NBUCK);
    bucket_scatter_kernel<<<256, 256, 0, stream>>>(src, dst, bfill, stg, E, NBUCK);
    bucket_place_kernel<<<NBUCK, 1024, 0, stream>>>(stg, bbase, rowptr, col, N, E);

    int agg_grid = (N + 3) / 4;

    // ---- layer 0 ----
    lin_mfma_kernel<IN_DIM, false><<<512, 256, 0, stream>>>(x, W0, b0, al0, ar0, HbfA, ALb, ARb, N, NTILES);
    agg_kernel<<<agg_grid, 256, 0, stream>>>(rowptr, col, ALb, ARb, HbfA, HbfB, N);
    // ---- layer 1 ----
    lin_mfma_kernel<HID, true><<<512, 256, 0, stream>>>(HbfB, W1, b1, al1, ar1, HbfA, ALb, ARb, N, NTILES);
    agg_kernel<<<agg_grid, 256, 0, stream>>>(rowptr, col, ALb, ARb, HbfA, HbfB, N);
    // ---- layer 2 ----
    lin_mfma_kernel<HID, true><<<512, 256, 0, stream>>>(HbfB, W2, b2, al2, ar2, HbfA, ALb, ARb, N, NTILES);
    agg_kernel<<<agg_grid, 256, 0, stream>>>(rowptr, col, ALb, ARb, HbfA, HbfB, N);
    // ---- post ----
    post_mfma_kernel<<<512, 256, 0, stream>>>(HbfB, Wp1, bp1, Wp2, bp2, out, N, NTILES);
}

// Round 10
// 272.421 us; speedup vs baseline: 1.4496x; 1.0778x over previous
//
#include <hip/hip_runtime.h>
#include <hip/hip_bf16.h>
#include <math.h>

// GNNStack: 3x GAT(heads=1, hid=64) + relu, then 64->64, 64->47, log_softmax.
//  - CSR build via two-level counting sort (no per-node global atomics).
//  - LIN/POST: MFMA 16x16x32 bf16, all inter-layer tensors bf16.
//  - alpha: SEPARATE kernel (R9 lesson: fusing the alpha shfl-reduce into
//    lin's epilogue put 128 ds_bpermute/thread on the LDS pipe -> 1.42M bank
//    conflicts, lin 2x slower. Cross-lane reduces don't belong in MFMA
//    epilogues). 4 nodes/wave, uint2 loads, 16-lane-group reduce.
//  - AGG: degree-adaptive gather, raw-exp softmax, denom in reduction.

#define IN_DIM 128
#define HID 64
#define OUT_DIM 47
#define NEG_SLOPE 0.2f
#define EPS 1e-16f
#define BBITS 10
#define BN 1024
#define NBUCK_MAX 128

typedef short bf16x8 __attribute__((ext_vector_type(8)));
typedef float f32x4 __attribute__((ext_vector_type(4)));

__device__ __forceinline__ float bflo(unsigned int d) {
    union { unsigned int i; float f; } c;
    c.i = d << 16;
    return c.f;
}
__device__ __forceinline__ float bfhi(unsigned int d) {
    union { unsigned int i; float f; } c;
    c.i = d & 0xffff0000u;
    return c.f;
}
__device__ __forceinline__ ushort f2bf(float f) {
    __hip_bfloat16 b = __float2bfloat16(f);
    return *(ushort*)&b;
}

// ---- CSR build ----
__global__ __launch_bounds__(256) void bucket_count_kernel(const int* __restrict__ dst,
                                                           int* __restrict__ bcnt,
                                                           int e, int nbuck) {
    __shared__ int h[NBUCK_MAX];
    int tid = threadIdx.x;
    if (tid < nbuck) h[tid] = 0;
    __syncthreads();
    int chunk = (e + gridDim.x - 1) / gridDim.x;
    int beg = blockIdx.x * chunk, end = min(e, beg + chunk);
    for (int i = beg + tid; i < end; i += 256) atomicAdd(&h[dst[i] >> BBITS], 1);
    __syncthreads();
    if (tid < nbuck && h[tid]) atomicAdd(&bcnt[tid], h[tid]);
}

__global__ void bucket_scan_kernel(const int* __restrict__ bcnt, int* __restrict__ bbase,
                                   int* __restrict__ bfill, int nbuck) {
    if (threadIdx.x == 0 && blockIdx.x == 0) {
        int run = 0;
        for (int i = 0; i < nbuck; i++) { bbase[i] = run; bfill[i] = run; run += bcnt[i]; }
        bbase[nbuck] = run;
    }
}

__global__ __launch_bounds__(256) void bucket_scatter_kernel(const int* __restrict__ src,
                                                             const int* __restrict__ dst,
                                                             int* __restrict__ bfill,
                                                             int2* __restrict__ stg,
                                                             int e, int nbuck) {
    __shared__ int lcnt[NBUCK_MAX], lfill[NBUCK_MAX];
    int tid = threadIdx.x;
    if (tid < nbuck) lcnt[tid] = 0;
    __syncthreads();
    int chunk = (e + gridDim.x - 1) / gridDim.x;
    int beg = blockIdx.x * chunk, end = min(e, beg + chunk);
    for (int i = beg + tid; i < end; i += 256) atomicAdd(&lcnt[dst[i] >> BBITS], 1);
    __syncthreads();
    if (tid < nbuck) lfill[tid] = lcnt[tid] ? atomicAdd(&bfill[tid], lcnt[tid]) : 0;
    __syncthreads();
    for (int i = beg + tid; i < end; i += 256) {
        int d = dst[i];
        int p = atomicAdd(&lfill[d >> BBITS], 1);
        stg[p] = make_int2(src[i], d);
    }
}

__global__ __launch_bounds__(1024) void bucket_place_kernel(const int2* __restrict__ stg,
                                                            const int* __restrict__ bbase,
                                                            int* __restrict__ rowptr,
                                                            int* __restrict__ col,
                                                            int n, int e) {
    __shared__ int lcnt[BN];
    __shared__ int lscan[BN];
    __shared__ int lfill[BN];
    int tid = threadIdx.x, b = blockIdx.x;
    int node0 = b << BBITS;
    int ebeg = bbase[b], eend = bbase[b + 1];
    lcnt[tid] = 0;
    __syncthreads();
    for (int j = ebeg + tid; j < eend; j += 1024) atomicAdd(&lcnt[stg[j].y - node0], 1);
    __syncthreads();
    int v = lcnt[tid];
    lscan[tid] = v;
    __syncthreads();
    for (int off = 1; off < 1024; off <<= 1) {
        int t = (tid >= off) ? lscan[tid - off] : 0;
        __syncthreads();
        lscan[tid] += t;
        __syncthreads();
    }
    int gbase = ebeg + lscan[tid] - v;
    if (node0 + tid < n) rowptr[node0 + tid] = gbase;
    lfill[tid] = gbase;
    __syncthreads();
    for (int j = ebeg + tid; j < eend; j += 1024) {
        int2 ed = stg[j];
        int p = atomicAdd(&lfill[ed.y - node0], 1);
        col[p] = ed.x;
    }
    if (b == 0 && tid == 0) rowptr[n] = e;
}

// ---- MFMA lin: H = bf16(X@W + b), tile = 64 nodes x 64 cols ----
template <int DIN, bool BF16IN>
__global__ __launch_bounds__(256) void lin_mfma_kernel(const void* __restrict__ Xin,
                                                       const float* __restrict__ W,
                                                       const float* __restrict__ B,
                                                       ushort* __restrict__ Hbf,
                                                       int n, int ntiles) {
    constexpr int PS = DIN + 8;
    __shared__ ushort Xl[64 * PS];
    __shared__ ushort Wt[64 * PS];  // Wt[c][k] = W[k][c]
    int tid = threadIdx.x;
    int lane = tid & 63;
    int cb = (tid >> 6) << 4;
    int colin = lane & 15, ksel = lane >> 4;
    for (int i = tid; i < DIN * 16; i += 256) {
        int k = i >> 4, cq = i & 15;
        float4 w = *(const float4*)&W[k * 64 + cq * 4];
        Wt[(cq * 4 + 0) * PS + k] = f2bf(w.x);
        Wt[(cq * 4 + 1) * PS + k] = f2bf(w.y);
        Wt[(cq * 4 + 2) * PS + k] = f2bf(w.z);
        Wt[(cq * 4 + 3) * PS + k] = f2bf(w.w);
    }
    float bc = B[cb + colin];
    for (int tile = blockIdx.x; tile < ntiles; tile += gridDim.x) {
        __syncthreads();  // guards Xl restage (and initial Wt stage)
        int node0 = tile << 6;
        if constexpr (BF16IN) {
            const ushort* Xb = (const ushort*)Xin;
            for (int i = tid; i < 64 * DIN / 8; i += 256) {
                int rr = i / (DIN / 8), ck = (i % (DIN / 8)) * 8;
                int gsrc = min(node0 + rr, n - 1);
                *(uint4*)&Xl[rr * PS + ck] = *(const uint4*)&Xb[(size_t)gsrc * DIN + ck];
            }
        } else {
            const float* Xf = (const float*)Xin;
            for (int i = tid; i < DIN * 16; i += 256) {
                int flat = i << 2;
                int rr = flat / DIN, kk = flat % DIN;
                int gsrc = min(node0 + rr, n - 1);
                float4 v = *(const float4*)&Xf[(size_t)gsrc * DIN + kk];
                ushort4 u;
                u.x = f2bf(v.x);
                u.y = f2bf(v.y);
                u.z = f2bf(v.z);
                u.w = f2bf(v.w);
                *(ushort4*)&Xl[rr * PS + kk] = u;
            }
        }
        __syncthreads();
        f32x4 acc[4];
#pragma unroll
        for (int rb = 0; rb < 4; rb++) acc[rb] = (f32x4){bc, bc, bc, bc};
#pragma unroll
        for (int ks = 0; ks < DIN; ks += 32) {
            bf16x8 bfr = *(const bf16x8*)&Wt[(cb + colin) * PS + ks + ksel * 8];
#pragma unroll
            for (int rb = 0; rb < 4; rb++) {
                bf16x8 afr = *(const bf16x8*)&Xl[(rb * 16 + colin) * PS + ks + ksel * 8];
                acc[rb] = __builtin_amdgcn_mfma_f32_16x16x32_bf16(afr, bfr, acc[rb], 0, 0, 0);
            }
        }
        // D layout: col = cb+colin, row = rb*16 + ksel*4 + r
#pragma unroll
        for (int rb = 0; rb < 4; rb++) {
#pragma unroll
            for (int r = 0; r < 4; r++) {
                int node = node0 + rb * 16 + ksel * 4 + r;
                if (node < n) Hbf[(size_t)node * 64 + cb + colin] = f2bf(acc[rb][r]);
            }
        }
    }
}

// ---- alpha: 4 nodes per wave; 16-lane group = one node row (uint2 loads) ----
__global__ __launch_bounds__(256) void alpha_kernel(const ushort* __restrict__ Hbf,
                                                    const float* __restrict__ attl,
                                                    const float* __restrict__ attr,
                                                    float* __restrict__ AL,
                                                    float* __restrict__ AR, int n) {
    int wv = threadIdx.x >> 6, lane = threadIdx.x & 63;
    int g = lane >> 4, li = lane & 15;
    int node = (blockIdx.x * 4 + wv) * 4 + g;
    if (node >= n) return;
    uint2 d = *(const uint2*)((const char*)Hbf + (((size_t)node) << 7) + (li << 3));
    float4 alv = *(const float4*)&attl[li * 4];
    float4 arv = *(const float4*)&attr[li * 4];
    float h0 = bflo(d.x), h1 = bfhi(d.x), h2 = bflo(d.y), h3 = bfhi(d.y);
    float pl = h0 * alv.x + h1 * alv.y + h2 * alv.z + h3 * alv.w;
    float pr = h0 * arv.x + h1 * arv.y + h2 * arv.z + h3 * arv.w;
#pragma unroll
    for (int o = 1; o < 16; o <<= 1) {
        pl += __shfl_xor(pl, o, 64);
        pr += __shfl_xor(pr, o, 64);
    }
    if (li == 0) {
        AL[node] = pl;
        AR[node] = pr;
    }
}

// ---- One wave per dst node: raw-exp softmax + degree-adaptive gather ----
__global__ __launch_bounds__(256) void agg_kernel(const int* __restrict__ rowptr,
                                                  const int* __restrict__ col,
                                                  const float* __restrict__ AL,
                                                  const float* __restrict__ AR,
                                                  const ushort* __restrict__ Hbf,
                                                  ushort* __restrict__ OUT, int n) {
    int wv = threadIdx.x >> 6, lane = threadIdx.x & 63;
    int nidx = blockIdx.x * 4 + wv;
    if (nidx >= n) return;
    int beg = rowptr[nidx], end = rowptr[nidx + 1];
    int deg = end - beg;
    float ar_i = AR[nidx];
    int g = lane >> 4;
    unsigned int sub = (lane & 15) << 3;
    float a0 = 0.f, a1 = 0.f, a2 = 0.f, a3 = 0.f, aw = 0.f;

    if (deg <= 32) {
        int c0 = 0;
        float x0 = 0.f;
        if (lane < deg) {
            c0 = col[beg + lane];
            float t = AL[c0] + ar_i;
            t = t > 0.f ? t : NEG_SLOPE * t;
            x0 = __expf(t);
        }
        {
            float w_[4];
            int s_[4];
#pragma unroll
            for (int t = 0; t < 4; t++) {
                int idx = t * 4 + g;
                w_[t] = __shfl(x0, idx, 64);
                s_[t] = __shfl(c0, idx, 64);
            }
            uint2 d_[4];
#pragma unroll
            for (int t = 0; t < 4; t++)
                d_[t] = *(const uint2*)((const char*)Hbf + ((((unsigned)s_[t]) << 7) + sub));
#pragma unroll
            for (int t = 0; t < 4; t++) {
                a0 = fmaf(w_[t], bflo(d_[t].x), a0);
                a1 = fmaf(w_[t], bfhi(d_[t].x), a1);
                a2 = fmaf(w_[t], bflo(d_[t].y), a2);
                a3 = fmaf(w_[t], bfhi(d_[t].y), a3);
                aw += w_[t];
            }
        }
        if (deg > 16) {
            float w_[4];
            int s_[4];
#pragma unroll
            for (int t = 0; t < 4; t++) {
                int idx = 16 + t * 4 + g;
                w_[t] = __shfl(x0, idx, 64);
                s_[t] = __shfl(c0, idx, 64);
            }
            uint2 d_[4];
#pragma unroll
            for (int t = 0; t < 4; t++)
                d_[t] = *(const uint2*)((const char*)Hbf + ((((unsigned)s_[t]) << 7) + sub));
#pragma unroll
            for (int t = 0; t < 4; t++) {
                a0 = fmaf(w_[t], bflo(d_[t].x), a0);
                a1 = fmaf(w_[t], bfhi(d_[t].x), a1);
                a2 = fmaf(w_[t], bflo(d_[t].y), a2);
                a3 = fmaf(w_[t], bfhi(d_[t].y), a3);
                aw += w_[t];
            }
        }
    } else {
        int c0 = 0;
        float x0 = 0.f;
        if (lane < deg) {
            c0 = col[beg + lane];
            float t = AL[c0] + ar_i;
            t = t > 0.f ? t : NEG_SLOPE * t;
            x0 = __expf(t);
        }
        int c1 = 0;
        float x1 = 0.f;
        if (64 + lane < deg) {
            c1 = col[beg + 64 + lane];
            float t = AL[c1] + ar_i;
            t = t > 0.f ? t : NEG_SLOPE * t;
            x1 = __expf(t);
        }
        int kend0 = deg < 64 ? deg : 64;
        for (int k = 0; k < kend0; k += 8) {
            int i0 = k + g, i1 = k + 4 + g;
            float w0 = __shfl(x0, i0, 64);
            int s0 = __shfl(c0, i0, 64);
            float w1 = __shfl(x0, i1, 64);
            int s1 = __shfl(c0, i1, 64);
            uint2 d0 = *(const uint2*)((const char*)Hbf + ((((unsigned)s0) << 7) + sub));
            uint2 d1 = *(const uint2*)((const char*)Hbf + ((((unsigned)s1) << 7) + sub));
            a0 = fmaf(w0, bflo(d0.x), a0);
            a1 = fmaf(w0, bfhi(d0.x), a1);
            a2 = fmaf(w0, bflo(d0.y), a2);
            a3 = fmaf(w0, bfhi(d0.y), a3);
            a0 = fmaf(w1, bflo(d1.x), a0);
            a1 = fmaf(w1, bfhi(d1.x), a1);
            a2 = fmaf(w1, bflo(d1.y), a2);
            a3 = fmaf(w1, bfhi(d1.y), a3);
            aw += w0 + w1;
        }
        if (deg > 64) {
            int kend1 = deg - 64 < 64 ? deg - 64 : 64;
            for (int k = 0; k < kend1; k += 8) {
                int i0 = k + g, i1 = k + 4 + g;
                float w0 = __shfl(x1, i0, 64);
                int s0 = __shfl(c1, i0, 64);
                float w1 = __shfl(x1, i1, 64);
                int s1 = __shfl(c1, i1, 64);
                uint2 d0 = *(const uint2*)((const char*)Hbf + ((((unsigned)s0) << 7) + sub));
                uint2 d1 = *(const uint2*)((const char*)Hbf + ((((unsigned)s1) << 7) + sub));
                a0 = fmaf(w0, bflo(d0.x), a0);
                a1 = fmaf(w0, bfhi(d0.x), a1);
                a2 = fmaf(w0, bflo(d0.y), a2);
                a3 = fmaf(w0, bfhi(d0.y), a3);
                a0 = fmaf(w1, bflo(d1.x), a0);
                a1 = fmaf(w1, bfhi(d1.x), a1);
                a2 = fmaf(w1, bflo(d1.y), a2);
                a3 = fmaf(w1, bfhi(d1.y), a3);
                aw += w0 + w1;
            }
            for (int j = beg + 128 + g; j < end; j += 4) {
                int s = col[j];
                float t = AL[s] + ar_i;
                t = t > 0.f ? t : NEG_SLOPE * t;
                float ex = __expf(t);
                uint2 d = *(const uint2*)((const char*)Hbf + ((((unsigned)s) << 7) + sub));
                a0 = fmaf(ex, bflo(d.x), a0);
                a1 = fmaf(ex, bfhi(d.x), a1);
                a2 = fmaf(ex, bflo(d.y), a2);
                a3 = fmaf(ex, bfhi(d.y), a3);
                aw += ex;
            }
        }
    }
    a0 += __shfl_xor(a0, 16, 64);
    a0 += __shfl_xor(a0, 32, 64);
    a1 += __shfl_xor(a1, 16, 64);
    a1 += __shfl_xor(a1, 32, 64);
    a2 += __shfl_xor(a2, 16, 64);
    a2 += __shfl_xor(a2, 32, 64);
    a3 += __shfl_xor(a3, 16, 64);
    a3 += __shfl_xor(a3, 32, 64);
    aw += __shfl_xor(aw, 16, 64);
    aw += __shfl_xor(aw, 32, 64);
    if (g == 0) {
        float r = 1.0f / (aw + EPS);
        float o0 = a0 * r, o1 = a1 * r, o2 = a2 * r, o3 = a3 * r;
        o0 = o0 > 0.f ? o0 : 0.f;
        o1 = o1 > 0.f ? o1 : 0.f;
        o2 = o2 > 0.f ? o2 : 0.f;
        o3 = o3 > 0.f ? o3 : 0.f;
        uint2 o;
        o.x = (unsigned int)f2bf(o0) | ((unsigned int)f2bf(o1) << 16);
        o.y = (unsigned int)f2bf(o2) | ((unsigned int)f2bf(o3) << 16);
        *(uint2*)((char*)OUT + (((size_t)nidx) << 7) + sub) = o;
    }
}

// ---- MFMA post (bf16 input): q = (h3@W1+b1)@W2+b2 ; log_softmax ----
__global__ __launch_bounds__(256) void post_mfma_kernel(const ushort* __restrict__ H3,
                                                        const float* __restrict__ Wp1,
                                                        const float* __restrict__ bp1,
                                                        const float* __restrict__ Wp2,
                                                        const float* __restrict__ bp2,
                                                        float* __restrict__ OUT,
                                                        int n, int ntiles) {
    constexpr int PS = 72;
    __shared__ ushort Hl[64 * PS];
    __shared__ ushort Pl[64 * PS];
    __shared__ ushort Wt1[64 * PS];
    __shared__ ushort Wt2[64 * PS];
    __shared__ float Ql[64 * PS];
    int tid = threadIdx.x;
    int lane = tid & 63;
    int cb = (tid >> 6) << 4;
    int colin = lane & 15, ksel = lane >> 4;
    for (int i = tid; i < 64 * 16; i += 256) {
        int k = i >> 4, cq = i & 15;
        float4 w1 = *(const float4*)&Wp1[k * 64 + cq * 4];
        Wt1[(cq * 4 + 0) * PS + k] = f2bf(w1.x);
        Wt1[(cq * 4 + 1) * PS + k] = f2bf(w1.y);
        Wt1[(cq * 4 + 2) * PS + k] = f2bf(w1.z);
        Wt1[(cq * 4 + 3) * PS + k] = f2bf(w1.w);
#pragma unroll
        for (int j = 0; j < 4; j++) {
            int c = cq * 4 + j;
            float w2 = (c < OUT_DIM) ? Wp2[k * OUT_DIM + c] : 0.f;
            Wt2[c * PS + k] = f2bf(w2);
        }
    }
    int myc = cb + colin;
    float bc1 = bp1[myc];
    float bc2 = (myc < OUT_DIM) ? bp2[myc] : 0.f;
    for (int tile = blockIdx.x; tile < ntiles; tile += gridDim.x) {
        __syncthreads();
        int node0 = tile << 6;
        for (int i = tid; i < 64 * 8; i += 256) {
            int rr = i >> 3, ck = (i & 7) << 3;
            int gsrc = min(node0 + rr, n - 1);
            *(uint4*)&Hl[rr * PS + ck] = *(const uint4*)&H3[(size_t)gsrc * 64 + ck];
        }
        __syncthreads();
        f32x4 acc1[4];
#pragma unroll
        for (int rb = 0; rb < 4; rb++) acc1[rb] = (f32x4){bc1, bc1, bc1, bc1};
#pragma unroll
        for (int ks = 0; ks < 64; ks += 32) {
            bf16x8 bfr = *(const bf16x8*)&Wt1[myc * PS + ks + ksel * 8];
#pragma unroll
            for (int rb = 0; rb < 4; rb++) {
                bf16x8 afr = *(const bf16x8*)&Hl[(rb * 16 + colin) * PS + ks + ksel * 8];
                acc1[rb] = __builtin_amdgcn_mfma_f32_16x16x32_bf16(afr, bfr, acc1[rb], 0, 0, 0);
            }
        }
#pragma unroll
        for (int rb = 0; rb < 4; rb++) {
#pragma unroll
            for (int r = 0; r < 4; r++) {
                int row = rb * 16 + ksel * 4 + r;
                Pl[row * PS + myc] = f2bf(acc1[rb][r]);
            }
        }
        __syncthreads();
        f32x4 acc2[4];
#pragma unroll
        for (int rb = 0; rb < 4; rb++) acc2[rb] = (f32x4){bc2, bc2, bc2, bc2};
#pragma unroll
        for (int ks = 0; ks < 64; ks += 32) {
            bf16x8 bfr = *(const bf16x8*)&Wt2[myc * PS + ks + ksel * 8];
#pragma unroll
            for (int rb = 0; rb < 4; rb++) {
                bf16x8 afr = *(const bf16x8*)&Pl[(rb * 16 + colin) * PS + ks + ksel * 8];
                acc2[rb] = __builtin_amdgcn_mfma_f32_16x16x32_bf16(afr, bfr, acc2[rb], 0, 0, 0);
            }
        }
#pragma unroll
        for (int rb = 0; rb < 4; rb++) {
#pragma unroll
            for (int r = 0; r < 4; r++) {
                int row = rb * 16 + ksel * 4 + r;
                Ql[row * PS + myc] = acc2[rb][r];
            }
        }
        __syncthreads();
        int nd = tid >> 2, part = tid & 3;
        int cbeg = part * 12;
        float m = -INFINITY;
#pragma unroll
        for (int i = 0; i < 12; i++) {
            int c = cbeg + i;
            if (c < OUT_DIM) m = fmaxf(m, Ql[nd * PS + c]);
        }
        m = fmaxf(m, __shfl_xor(m, 1, 64));
        m = fmaxf(m, __shfl_xor(m, 2, 64));
        float s = 0.f;
#pragma unroll
        for (int i = 0; i < 12; i++) {
            int c = cbeg + i;
            if (c < OUT_DIM) s += __expf(Ql[nd * PS + c] - m);
        }
        s += __shfl_xor(s, 1, 64);
        s += __shfl_xor(s, 2, 64);
        float lg = m + __logf(s);
        int node = node0 + nd;
        if (node < n) {
#pragma unroll
            for (int i = 0; i < 12; i++) {
                int c = cbeg + i;
                if (c < OUT_DIM) OUT[(size_t)node * OUT_DIM + c] = Ql[nd * PS + c] - lg;
            }
        }
    }
}

extern "C" void kernel_launch(void* const* d_in, const int* in_sizes, int n_in,
                              void* d_out, int out_size, void* d_ws, size_t ws_size,
                              hipStream_t stream) {
    const float* x = (const float*)d_in[0];
    const int* ei = (const int*)d_in[1];
    const float* W0 = (const float*)d_in[2];
    const float* b0 = (const float*)d_in[3];
    const float* al0 = (const float*)d_in[4];
    const float* ar0 = (const float*)d_in[5];
    const float* W1 = (const float*)d_in[6];
    const float* b1 = (const float*)d_in[7];
    const float* al1 = (const float*)d_in[8];
    const float* ar1 = (const float*)d_in[9];
    const float* W2 = (const float*)d_in[10];
    const float* b2 = (const float*)d_in[11];
    const float* al2 = (const float*)d_in[12];
    const float* ar2 = (const float*)d_in[13];
    const float* Wp1 = (const float*)d_in[14];
    const float* bp1 = (const float*)d_in[15];
    const float* Wp2 = (const float*)d_in[16];
    const float* bp2 = (const float*)d_in[17];
    float* out = (float*)d_out;

    const int N = in_sizes[0] / IN_DIM;
    const int E = in_sizes[1] / 2;
    const int NBUCK = (N + BN - 1) >> BBITS;
    const int NTILES = (N + 63) >> 6;

    char* ws = (char*)d_ws;
    ushort* HbfA = (ushort*)ws;  ws += (size_t)N * 64 * sizeof(ushort);  // lin out / agg in
    ushort* HbfB = (ushort*)ws;  ws += (size_t)N * 64 * sizeof(ushort);  // agg out / lin in
    float* ALb = (float*)ws;     ws += (size_t)N * sizeof(float);
    float* ARb = (float*)ws;     ws += (size_t)N * sizeof(float);
    int* rowptr = (int*)ws;      ws += (size_t)(N + 1) * sizeof(int);
    int* col = (int*)ws;         ws += (size_t)E * sizeof(int);
    int* bcnt = (int*)ws;        ws += (size_t)NBUCK * sizeof(int);
    int* bbase = (int*)ws;       ws += (size_t)(NBUCK + 1) * sizeof(int);
    int* bfill = (int*)ws;       ws += (size_t)NBUCK * sizeof(int);
    int2* stg = (int2*)ws;       ws += (size_t)E * sizeof(int2);

    const int* src = ei;
    const int* dst = ei + E;

    hipMemsetAsync(bcnt, 0, (size_t)NBUCK * sizeof(int), stream);
    bucket_count_kernel<<<256, 256, 0, stream>>>(dst, bcnt, E, NBUCK);
    bucket_scan_kernel<<<1, 64, 0, stream>>>(bcnt, bbase, bfill, NBUCK);
    bucket_scatter_kernel<<<256, 256, 0, stream>>>(src, dst, bfill, stg, E, NBUCK);
    bucket_place_kernel<<<NBUCK, 1024, 0, stream>>>(stg, bbase, rowptr, col, N, E);

    int agg_grid = (N + 3) / 4;
    int alpha_grid = (N + 15) / 16;

    // ---- layer 0 ----
    lin_mfma_kernel<IN_DIM, false><<<512, 256, 0, stream>>>(x, W0, b0, HbfA, N, NTILES);
    alpha_kernel<<<alpha_grid, 256, 0, stream>>>(HbfA, al0, ar0, ALb, ARb, N);
    agg_kernel<<<agg_grid, 256, 0, stream>>>(rowptr, col, ALb, ARb, HbfA, HbfB, N);
    // ---- layer 1 ----
    lin_mfma_kernel<HID, true><<<512, 256, 0, stream>>>(HbfB, W1, b1, HbfA, N, NTILES);
    alpha_kernel<<<alpha_grid, 256, 0, stream>>>(HbfA, al1, ar1, ALb, ARb, N);
    agg_kernel<<<agg_grid, 256, 0, stream>>>(rowptr, col, ALb, ARb, HbfA, HbfB, N);
    // ---- layer 2 ----
    lin_mfma_kernel<HID, true><<<512, 256, 0, stream>>>(HbfB, W2, b2, HbfA, N, NTILES);
    alpha_kernel<<<alpha_grid, 256, 0, stream>>>(HbfA, al2, ar2, ALb, ARb, N);
    agg_kernel<<<agg_grid, 256, 0, stream>>>(rowptr, col, ALb, ARb, HbfA, HbfB, N);
    // ---- post ----
    post_mfma_kernel<<<512, 256, 0, stream>>>(HbfB, Wp1, bp1, Wp2, bp2, out, N, NTILES);
}

// Round 11
// 270.076 us; speedup vs baseline: 1.4622x; 1.0087x over previous
//
#include <hip/hip_runtime.h>
#include <hip/hip_bf16.h>
#include <math.h>

// GNNStack: 3x GAT(heads=1, hid=64) + relu, then 64->64, 64->47, log_softmax.
//  - CSR build via two-level counting sort (no per-node global atomics).
//  - LIN/POST: MFMA 16x16x32 bf16, all inter-layer tensors bf16.
//  - alpha: separate kernel (R9 lesson: cross-lane reduces don't belong in
//    MFMA epilogues — 128 bpermute/thread = 1.4M bank conflicts).
//  - AGG R11: 16-lane group = one node (4 nodes/wave). Kills the 26 LDS-pipe
//    ops/node of the R10 shfl structure (measured ~60% of agg time): pairs
//    (w,src) go through an LDS pair buffer — 1 ds_write_b64 + broadcast
//    ds_read_b64 per edge-slot, no cross-group reduce (denominator is
//    replicated per lane). Gather loads batched 8-deep.

#define IN_DIM 128
#define HID 64
#define OUT_DIM 47
#define NEG_SLOPE 0.2f
#define EPS 1e-16f
#define BBITS 10
#define BN 1024
#define NBUCK_MAX 128

typedef short bf16x8 __attribute__((ext_vector_type(8)));
typedef float f32x4 __attribute__((ext_vector_type(4)));

__device__ __forceinline__ float bflo(unsigned int d) {
    union { unsigned int i; float f; } c;
    c.i = d << 16;
    return c.f;
}
__device__ __forceinline__ float bfhi(unsigned int d) {
    union { unsigned int i; float f; } c;
    c.i = d & 0xffff0000u;
    return c.f;
}
__device__ __forceinline__ ushort f2bf(float f) {
    __hip_bfloat16 b = __float2bfloat16(f);
    return *(ushort*)&b;
}

// ---- CSR build ----
__global__ __launch_bounds__(256) void bucket_count_kernel(const int* __restrict__ dst,
                                                           int* __restrict__ bcnt,
                                                           int e, int nbuck) {
    __shared__ int h[NBUCK_MAX];
    int tid = threadIdx.x;
    if (tid < nbuck) h[tid] = 0;
    __syncthreads();
    int chunk = (e + gridDim.x - 1) / gridDim.x;
    int beg = blockIdx.x * chunk, end = min(e, beg + chunk);
    for (int i = beg + tid; i < end; i += 256) atomicAdd(&h[dst[i] >> BBITS], 1);
    __syncthreads();
    if (tid < nbuck && h[tid]) atomicAdd(&bcnt[tid], h[tid]);
}

__global__ void bucket_scan_kernel(const int* __restrict__ bcnt, int* __restrict__ bbase,
                                   int* __restrict__ bfill, int nbuck) {
    if (threadIdx.x == 0 && blockIdx.x == 0) {
        int run = 0;
        for (int i = 0; i < nbuck; i++) { bbase[i] = run; bfill[i] = run; run += bcnt[i]; }
        bbase[nbuck] = run;
    }
}

__global__ __launch_bounds__(256) void bucket_scatter_kernel(const int* __restrict__ src,
                                                             const int* __restrict__ dst,
                                                             int* __restrict__ bfill,
                                                             int2* __restrict__ stg,
                                                             int e, int nbuck) {
    __shared__ int lcnt[NBUCK_MAX], lfill[NBUCK_MAX];
    int tid = threadIdx.x;
    if (tid < nbuck) lcnt[tid] = 0;
    __syncthreads();
    int chunk = (e + gridDim.x - 1) / gridDim.x;
    int beg = blockIdx.x * chunk, end = min(e, beg + chunk);
    for (int i = beg + tid; i < end; i += 256) atomicAdd(&lcnt[dst[i] >> BBITS], 1);
    __syncthreads();
    if (tid < nbuck) lfill[tid] = lcnt[tid] ? atomicAdd(&bfill[tid], lcnt[tid]) : 0;
    __syncthreads();
    for (int i = beg + tid; i < end; i += 256) {
        int d = dst[i];
        int p = atomicAdd(&lfill[d >> BBITS], 1);
        stg[p] = make_int2(src[i], d);
    }
}

__global__ __launch_bounds__(1024) void bucket_place_kernel(const int2* __restrict__ stg,
                                                            const int* __restrict__ bbase,
                                                            int* __restrict__ rowptr,
                                                            int* __restrict__ col,
                                                            int n, int e) {
    __shared__ int lcnt[BN];
    __shared__ int lscan[BN];
    __shared__ int lfill[BN];
    int tid = threadIdx.x, b = blockIdx.x;
    int node0 = b << BBITS;
    int ebeg = bbase[b], eend = bbase[b + 1];
    lcnt[tid] = 0;
    __syncthreads();
    for (int j = ebeg + tid; j < eend; j += 1024) atomicAdd(&lcnt[stg[j].y - node0], 1);
    __syncthreads();
    int v = lcnt[tid];
    lscan[tid] = v;
    __syncthreads();
    for (int off = 1; off < 1024; off <<= 1) {
        int t = (tid >= off) ? lscan[tid - off] : 0;
        __syncthreads();
        lscan[tid] += t;
        __syncthreads();
    }
    int gbase = ebeg + lscan[tid] - v;
    if (node0 + tid < n) rowptr[node0 + tid] = gbase;
    lfill[tid] = gbase;
    __syncthreads();
    for (int j = ebeg + tid; j < eend; j += 1024) {
        int2 ed = stg[j];
        int p = atomicAdd(&lfill[ed.y - node0], 1);
        col[p] = ed.x;
    }
    if (b == 0 && tid == 0) rowptr[n] = e;
}

// ---- MFMA lin: H = bf16(X@W + b), tile = 64 nodes x 64 cols ----
template <int DIN, bool BF16IN>
__global__ __launch_bounds__(256) void lin_mfma_kernel(const void* __restrict__ Xin,
                                                       const float* __restrict__ W,
                                                       const float* __restrict__ B,
                                                       ushort* __restrict__ Hbf,
                                                       int n, int ntiles) {
    constexpr int PS = DIN + 8;
    __shared__ ushort Xl[64 * PS];
    __shared__ ushort Wt[64 * PS];  // Wt[c][k] = W[k][c]
    int tid = threadIdx.x;
    int lane = tid & 63;
    int cb = (tid >> 6) << 4;
    int colin = lane & 15, ksel = lane >> 4;
    for (int i = tid; i < DIN * 16; i += 256) {
        int k = i >> 4, cq = i & 15;
        float4 w = *(const float4*)&W[k * 64 + cq * 4];
        Wt[(cq * 4 + 0) * PS + k] = f2bf(w.x);
        Wt[(cq * 4 + 1) * PS + k] = f2bf(w.y);
        Wt[(cq * 4 + 2) * PS + k] = f2bf(w.z);
        Wt[(cq * 4 + 3) * PS + k] = f2bf(w.w);
    }
    float bc = B[cb + colin];
    for (int tile = blockIdx.x; tile < ntiles; tile += gridDim.x) {
        __syncthreads();  // guards Xl restage (and initial Wt stage)
        int node0 = tile << 6;
        if constexpr (BF16IN) {
            const ushort* Xb = (const ushort*)Xin;
            for (int i = tid; i < 64 * DIN / 8; i += 256) {
                int rr = i / (DIN / 8), ck = (i % (DIN / 8)) * 8;
                int gsrc = min(node0 + rr, n - 1);
                *(uint4*)&Xl[rr * PS + ck] = *(const uint4*)&Xb[(size_t)gsrc * DIN + ck];
            }
        } else {
            const float* Xf = (const float*)Xin;
            for (int i = tid; i < DIN * 16; i += 256) {
                int flat = i << 2;
                int rr = flat / DIN, kk = flat % DIN;
                int gsrc = min(node0 + rr, n - 1);
                float4 v = *(const float4*)&Xf[(size_t)gsrc * DIN + kk];
                ushort4 u;
                u.x = f2bf(v.x);
                u.y = f2bf(v.y);
                u.z = f2bf(v.z);
                u.w = f2bf(v.w);
                *(ushort4*)&Xl[rr * PS + kk] = u;
            }
        }
        __syncthreads();
        f32x4 acc[4];
#pragma unroll
        for (int rb = 0; rb < 4; rb++) acc[rb] = (f32x4){bc, bc, bc, bc};
#pragma unroll
        for (int ks = 0; ks < DIN; ks += 32) {
            bf16x8 bfr = *(const bf16x8*)&Wt[(cb + colin) * PS + ks + ksel * 8];
#pragma unroll
            for (int rb = 0; rb < 4; rb++) {
                bf16x8 afr = *(const bf16x8*)&Xl[(rb * 16 + colin) * PS + ks + ksel * 8];
                acc[rb] = __builtin_amdgcn_mfma_f32_16x16x32_bf16(afr, bfr, acc[rb], 0, 0, 0);
            }
        }
        // D layout: col = cb+colin, row = rb*16 + ksel*4 + r
#pragma unroll
        for (int rb = 0; rb < 4; rb++) {
#pragma unroll
            for (int r = 0; r < 4; r++) {
                int node = node0 + rb * 16 + ksel * 4 + r;
                if (node < n) Hbf[(size_t)node * 64 + cb + colin] = f2bf(acc[rb][r]);
            }
        }
    }
}

// ---- alpha: 4 nodes per wave; 16-lane group = one node row (uint2 loads) ----
__global__ __launch_bounds__(256) void alpha_kernel(const ushort* __restrict__ Hbf,
                                                    const float* __restrict__ attl,
                                                    const float* __restrict__ attr,
                                                    float* __restrict__ AL,
                                                    float* __restrict__ AR, int n) {
    int wv = threadIdx.x >> 6, lane = threadIdx.x & 63;
    int g = lane >> 4, li = lane & 15;
    int node = (blockIdx.x * 4 + wv) * 4 + g;
    if (node >= n) return;
    uint2 d = *(const uint2*)((const char*)Hbf + (((size_t)node) << 7) + (li << 3));
    float4 alv = *(const float4*)&attl[li * 4];
    float4 arv = *(const float4*)&attr[li * 4];
    float h0 = bflo(d.x), h1 = bfhi(d.x), h2 = bflo(d.y), h3 = bfhi(d.y);
    float pl = h0 * alv.x + h1 * alv.y + h2 * alv.z + h3 * alv.w;
    float pr = h0 * arv.x + h1 * arv.y + h2 * arv.z + h3 * arv.w;
#pragma unroll
    for (int o = 1; o < 16; o <<= 1) {
        pl += __shfl_xor(pl, o, 64);
        pr += __shfl_xor(pr, o, 64);
    }
    if (li == 0) {
        AL[node] = pl;
        AR[node] = pr;
    }
}

// ---- AGG: 16-lane group = one node; LDS pair buffer; no cross-group reduce ----
__global__ __launch_bounds__(256) void agg_kernel(const int* __restrict__ rowptr,
                                                  const int* __restrict__ col,
                                                  const float* __restrict__ AL,
                                                  const float* __restrict__ AR,
                                                  const ushort* __restrict__ Hbf,
                                                  ushort* __restrict__ OUT, int n) {
    __shared__ uint2 pairbuf[4][4][17];  // [wave][group][slot], stride 17: 4 groups on distinct banks
    int tid = threadIdx.x;
    int wv = tid >> 6, lane = tid & 63;
    int g = lane >> 4, li = lane & 15;
    int nidx = blockIdx.x * 16 + wv * 4 + g;
    bool valid = nidx < n;
    int beg = 0, deg = 0;
    float ar_i = 0.f;
    if (valid) {
        beg = rowptr[nidx];
        deg = rowptr[nidx + 1] - beg;
        ar_i = AR[nidx];
    }
    const char* hb = (const char*)Hbf + (li << 3);  // lane's 8B slice within a row
    float a0 = 0.f, a1 = 0.f, a2 = 0.f, a3 = 0.f, aw = 0.f;
    for (int base = 0; base < deg; base += 16) {
        int e = base + li;
        float x = 0.f;
        int c = 0;
        if (e < deg) {
            c = col[beg + e];
            float t = AL[c] + ar_i;
            t = t > 0.f ? t : NEG_SLOPE * t;
            x = __expf(t);
        }
        // pad slots (e >= deg) carry x=0 -> branchless-safe reads below.
        pairbuf[wv][g][li] = make_uint2(__float_as_uint(x), (unsigned)c);
        int cnt = deg - base;
        if (cnt > 16) cnt = 16;
        if (cnt == 16) {  // hot full-slot path: 8 loads in flight per half
#pragma unroll
            for (int h = 0; h < 2; h++) {
                uint2 pc[8];
#pragma unroll
                for (int t = 0; t < 8; t++) pc[t] = pairbuf[wv][g][h * 8 + t];
                uint2 d[8];
#pragma unroll
                for (int t = 0; t < 8; t++)
                    d[t] = *(const uint2*)(hb + (((size_t)pc[t].y) << 7));
#pragma unroll
                for (int t = 0; t < 8; t++) {
                    float w = __uint_as_float(pc[t].x);
                    a0 = fmaf(w, bflo(d[t].x), a0);
                    a1 = fmaf(w, bfhi(d[t].x), a1);
                    a2 = fmaf(w, bflo(d[t].y), a2);
                    a3 = fmaf(w, bfhi(d[t].y), a3);
                    aw += w;
                }
            }
        } else {  // tail: 4-wide steps; overshoot slots have w=0
            for (int t0 = 0; t0 < cnt; t0 += 4) {
                uint2 pc[4];
#pragma unroll
                for (int t = 0; t < 4; t++) {
                    int s = t0 + t;
                    pc[t] = pairbuf[wv][g][s < 16 ? s : 15];
                }
                uint2 d[4];
#pragma unroll
                for (int t = 0; t < 4; t++)
                    d[t] = *(const uint2*)(hb + (((size_t)pc[t].y) << 7));
#pragma unroll
                for (int t = 0; t < 4; t++) {
                    float w = __uint_as_float(pc[t].x);
                    a0 = fmaf(w, bflo(d[t].x), a0);
                    a1 = fmaf(w, bfhi(d[t].x), a1);
                    a2 = fmaf(w, bflo(d[t].y), a2);
                    a3 = fmaf(w, bfhi(d[t].y), a3);
                    aw += w;
                }
            }
        }
    }
    if (valid) {
        float r = 1.0f / (aw + EPS);
        float o0 = a0 * r, o1 = a1 * r, o2 = a2 * r, o3 = a3 * r;
        o0 = o0 > 0.f ? o0 : 0.f;
        o1 = o1 > 0.f ? o1 : 0.f;
        o2 = o2 > 0.f ? o2 : 0.f;
        o3 = o3 > 0.f ? o3 : 0.f;
        uint2 o;
        o.x = (unsigned int)f2bf(o0) | ((unsigned int)f2bf(o1) << 16);
        o.y = (unsigned int)f2bf(o2) | ((unsigned int)f2bf(o3) << 16);
        *(uint2*)((char*)OUT + (((size_t)nidx) << 7) + (li << 3)) = o;
    }
}

// ---- MFMA post (bf16 input): q = (h3@W1+b1)@W2+b2 ; log_softmax ----
__global__ __launch_bounds__(256) void post_mfma_kernel(const ushort* __restrict__ H3,
                                                        const float* __restrict__ Wp1,
                                                        const float* __restrict__ bp1,
                                                        const float* __restrict__ Wp2,
                                                        const float* __restrict__ bp2,
                                                        float* __restrict__ OUT,
                                                        int n, int ntiles) {
    constexpr int PS = 72;
    __shared__ ushort Hl[64 * PS];
    __shared__ ushort Pl[64 * PS];
    __shared__ ushort Wt1[64 * PS];
    __shared__ ushort Wt2[64 * PS];
    __shared__ float Ql[64 * PS];
    int tid = threadIdx.x;
    int lane = tid & 63;
    int cb = (tid >> 6) << 4;
    int colin = lane & 15, ksel = lane >> 4;
    for (int i = tid; i < 64 * 16; i += 256) {
        int k = i >> 4, cq = i & 15;
        float4 w1 = *(const float4*)&Wp1[k * 64 + cq * 4];
        Wt1[(cq * 4 + 0) * PS + k] = f2bf(w1.x);
        Wt1[(cq * 4 + 1) * PS + k] = f2bf(w1.y);
        Wt1[(cq * 4 + 2) * PS + k] = f2bf(w1.z);
        Wt1[(cq * 4 + 3) * PS + k] = f2bf(w1.w);
#pragma unroll
        for (int j = 0; j < 4; j++) {
            int c = cq * 4 + j;
            float w2 = (c < OUT_DIM) ? Wp2[k * OUT_DIM + c] : 0.f;
            Wt2[c * PS + k] = f2bf(w2);
        }
    }
    int myc = cb + colin;
    float bc1 = bp1[myc];
    float bc2 = (myc < OUT_DIM) ? bp2[myc] : 0.f;
    for (int tile = blockIdx.x; tile < ntiles; tile += gridDim.x) {
        __syncthreads();
        int node0 = tile << 6;
        for (int i = tid; i < 64 * 8; i += 256) {
            int rr = i >> 3, ck = (i & 7) << 3;
            int gsrc = min(node0 + rr, n - 1);
            *(uint4*)&Hl[rr * PS + ck] = *(const uint4*)&H3[(size_t)gsrc * 64 + ck];
        }
        __syncthreads();
        f32x4 acc1[4];
#pragma unroll
        for (int rb = 0; rb < 4; rb++) acc1[rb] = (f32x4){bc1, bc1, bc1, bc1};
#pragma unroll
        for (int ks = 0; ks < 64; ks += 32) {
            bf16x8 bfr = *(const bf16x8*)&Wt1[myc * PS + ks + ksel * 8];
#pragma unroll
            for (int rb = 0; rb < 4; rb++) {
                bf16x8 afr = *(const bf16x8*)&Hl[(rb * 16 + colin) * PS + ks + ksel * 8];
                acc1[rb] = __builtin_amdgcn_mfma_f32_16x16x32_bf16(afr, bfr, acc1[rb], 0, 0, 0);
            }
        }
#pragma unroll
        for (int rb = 0; rb < 4; rb++) {
#pragma unroll
            for (int r = 0; r < 4; r++) {
                int row = rb * 16 + ksel * 4 + r;
                Pl[row * PS + myc] = f2bf(acc1[rb][r]);
            }
        }
        __syncthreads();
        f32x4 acc2[4];
#pragma unroll
        for (int rb = 0; rb < 4; rb++) acc2[rb] = (f32x4){bc2, bc2, bc2, bc2};
#pragma unroll
        for (int ks = 0; ks < 64; ks += 32) {
            bf16x8 bfr = *(const bf16x8*)&Wt2[myc * PS + ks + ksel * 8];
#pragma unroll
            for (int rb = 0; rb < 4; rb++) {
                bf16x8 afr = *(const bf16x8*)&Pl[(rb * 16 + colin) * PS + ks + ksel * 8];
                acc2[rb] = __builtin_amdgcn_mfma_f32_16x16x32_bf16(afr, bfr, acc2[rb], 0, 0, 0);
            }
        }
#pragma unroll
        for (int rb = 0; rb < 4; rb++) {
#pragma unroll
            for (int r = 0; r < 4; r++) {
                int row = rb * 16 + ksel * 4 + r;
                Ql[row * PS + myc] = acc2[rb][r];
            }
        }
        __syncthreads();
        int nd = tid >> 2, part = tid & 3;
        int cbeg = part * 12;
        float m = -INFINITY;
#pragma unroll
        for (int i = 0; i < 12; i++) {
            int c = cbeg + i;
            if (c < OUT_DIM) m = fmaxf(m, Ql[nd * PS + c]);
        }
        m = fmaxf(m, __shfl_xor(m, 1, 64));
        m = fmaxf(m, __shfl_xor(m, 2, 64));
        float s = 0.f;
#pragma unroll
        for (int i = 0; i < 12; i++) {
            int c = cbeg + i;
            if (c < OUT_DIM) s += __expf(Ql[nd * PS + c] - m);
        }
        s += __shfl_xor(s, 1, 64);
        s += __shfl_xor(s, 2, 64);
        float lg = m + __logf(s);
        int node = node0 + nd;
        if (node < n) {
#pragma unroll
            for (int i = 0; i < 12; i++) {
                int c = cbeg + i;
                if (c < OUT_DIM) OUT[(size_t)node * OUT_DIM + c] = Ql[nd * PS + c] - lg;
            }
        }
    }
}

extern "C" void kernel_launch(void* const* d_in, const int* in_sizes, int n_in,
                              void* d_out, int out_size, void* d_ws, size_t ws_size,
                              hipStream_t stream) {
    const float* x = (const float*)d_in[0];
    const int* ei = (const int*)d_in[1];
    const float* W0 = (const float*)d_in[2];
    const float* b0 = (const float*)d_in[3];
    const float* al0 = (const float*)d_in[4];
    const float* ar0 = (const float*)d_in[5];
    const float* W1 = (const float*)d_in[6];
    const float* b1 = (const float*)d_in[7];
    const float* al1 = (const float*)d_in[8];
    const float* ar1 = (const float*)d_in[9];
    const float* W2 = (const float*)d_in[10];
    const float* b2 = (const float*)d_in[11];
    const float* al2 = (const float*)d_in[12];
    const float* ar2 = (const float*)d_in[13];
    const float* Wp1 = (const float*)d_in[14];
    const float* bp1 = (const float*)d_in[15];
    const float* Wp2 = (const float*)d_in[16];
    const float* bp2 = (const float*)d_in[17];
    float* out = (float*)d_out;

    const int N = in_sizes[0] / IN_DIM;
    const int E = in_sizes[1] / 2;
    const int NBUCK = (N + BN - 1) >> BBITS;
    const int NTILES = (N + 63) >> 6;

    char* ws = (char*)d_ws;
    ushort* HbfA = (ushort*)ws;  ws += (size_t)N * 64 * sizeof(ushort);  // lin out / agg in
    ushort* HbfB = (ushort*)ws;  ws += (size_t)N * 64 * sizeof(ushort);  // agg out / lin in
    float* ALb = (float*)ws;     ws += (size_t)N * sizeof(float);
    float* ARb = (float*)ws;     ws += (size_t)N * sizeof(float);
    int* rowptr = (int*)ws;      ws += (size_t)(N + 1) * sizeof(int);
    int* col = (int*)ws;         ws += (size_t)E * sizeof(int);
    int* bcnt = (int*)ws;        ws += (size_t)NBUCK * sizeof(int);
    int* bbase = (int*)ws;       ws += (size_t)(NBUCK + 1) * sizeof(int);
    int* bfill = (int*)ws;       ws += (size_t)NBUCK * sizeof(int);
    int2* stg = (int2*)ws;       ws += (size_t)E * sizeof(int2);

    const int* src = ei;
    const int* dst = ei + E;

    hipMemsetAsync(bcnt, 0, (size_t)NBUCK * sizeof(int), stream);
    bucket_count_kernel<<<256, 256, 0, stream>>>(dst, bcnt, E, NBUCK);
    bucket_scan_kernel<<<1, 64, 0, stream>>>(bcnt, bbase, bfill, NBUCK);
    bucket_scatter_kernel<<<256, 256, 0, stream>>>(src, dst, bfill, stg, E, NBUCK);
    bucket_place_kernel<<<NBUCK, 1024, 0, stream>>>(stg, bbase, rowptr, col, N, E);

    int agg_grid = (N + 15) / 16;
    int alpha_grid = (N + 15) / 16;

    // ---- layer 0 ----
    lin_mfma_kernel<IN_DIM, false><<<512, 256, 0, stream>>>(x, W0, b0, HbfA, N, NTILES);
    alpha_kernel<<<alpha_grid, 256, 0, stream>>>(HbfA, al0, ar0, ALb, ARb, N);
    agg_kernel<<<agg_grid, 256, 0, stream>>>(rowptr, col, ALb, ARb, HbfA, HbfB, N);
    // ---- layer 1 ----
    lin_mfma_kernel<HID, true><<<512, 256, 0, stream>>>(HbfB, W1, b1, HbfA, N, NTILES);
    alpha_kernel<<<alpha_grid, 256, 0, stream>>>(HbfA, al1, ar1, ALb, ARb, N);
    agg_kernel<<<agg_grid, 256, 0, stream>>>(rowptr, col, ALb, ARb, HbfA, HbfB, N);
    // ---- layer 2 ----
    lin_mfma_kernel<HID, true><<<512, 256, 0, stream>>>(HbfB, W2, b2, HbfA, N, NTILES);
    alpha_kernel<<<alpha_grid, 256, 0, stream>>>(HbfA, al2, ar2, ALb, ARb, N);
    agg_kernel<<<agg_grid, 256, 0, stream>>>(rowptr, col, ALb, ARb, HbfA, HbfB, N);
    // ---- post ----
    post_mfma_kernel<<<512, 256, 0, stream>>>(HbfB, Wp1, bp1, Wp2, bp2, out, N, NTILES);
}